// Round 5
// baseline (342.354 us; speedup 1.0000x reference)
//
#include <hip/hip_runtime.h>
#include <cstdint>

#define N_ 16
#define C_ 256
#define H_ 64
#define W_ 64
#define L_ 4096          // H*W
#define K_ 32
#define CL_ (C_*L_)      // 1048576
#define KL_ (K_*L_)      // 131072
#define KC_ (K_*C_)      // 8192

typedef __attribute__((ext_vector_type(8))) short short8;   // 8 bf16 (4 VGPRs)
typedef __attribute__((ext_vector_type(4))) float f32x4;    // MFMA C/D frag

__device__ __forceinline__ unsigned short f2bf(float x) {   // RNE fp32->bf16
    unsigned int u = __float_as_uint(x);
    u += 0x7fffu + ((u >> 16) & 1u);
    return (unsigned short)(u >> 16);
}
__device__ __forceinline__ unsigned int pack2(float a, float b) {
    return (unsigned int)f2bf(a) | ((unsigned int)f2bf(b) << 16);
}

// ---------- K1: fused rinv + xn(bf16) transposed to (n,l,c) ----------
__global__ __launch_bounds__(256) void k_prep(
    const float* __restrict__ f, float* __restrict__ rinv,
    unsigned short* __restrict__ xnb)
{
    __shared__ float tile[256 * 34];            // [c][l], stride 34 (conflict-free)
    __shared__ float ssred[8 * 33];
    __shared__ float rbuf[32];
    int bid = blockIdx.x;
    int n = bid >> 7;
    int l0 = (bid & 127) << 5;
    int tid = threadIdx.x;
    int l = tid & 31, cb = tid >> 5;            // cb 0..7
    const float* fp = f + (size_t)n * CL_ + l0 + l;
    float ss = 0.f;
#pragma unroll
    for (int i = 0; i < 32; ++i) {
        int c = (cb << 5) + i;
        float v = fp[(size_t)c * L_];
        tile[c * 34 + l] = v;
        ss = fmaf(v, v, ss);
    }
    ssred[cb * 33 + l] = ss;
    __syncthreads();
    if (tid < 32) {
        float s = 0.f;
#pragma unroll
        for (int j = 0; j < 8; ++j) s += ssred[j * 33 + tid];
        float ri = 1.0f / fmaxf(sqrtf(s), 1e-12f);
        rinv[n * L_ + l0 + tid] = ri;
        rbuf[tid] = ri;
    }
    __syncthreads();
    float ri = rbuf[l];
    unsigned short* op = xnb + ((size_t)n * L_ + l0 + l) * C_ + (cb << 5);
#pragma unroll
    for (int g = 0; g < 4; ++g) {
        unsigned int pk[4];
#pragma unroll
        for (int d = 0; d < 4; ++d) {
            int c = (cb << 5) + (g << 3) + (d << 1);
            pk[d] = pack2(tile[c * 34 + l] * ri, tile[(c + 1) * 34 + l] * ri);
        }
        *(uint4*)(op + (g << 3)) = make_uint4(pk[0], pk[1], pk[2], pk[3]);
    }
}

// ---------- K2: repack conv weights -> wb[t][ch][q][k][8] bf16 ----------
// linear = ((t*8 + ch)*4 + q)*256 + k*8 + j, with c = ch*32+q*8+j.
// A-fragment load for lane (r,quad): wb + ((t*8+ch)*4+quad)*256 + r*8 ->
// consecutive r lanes CONTIGUOUS 16B -> 4x256B segments per instruction.
__global__ __launch_bounds__(256) void k_wpack(const float* __restrict__ w, unsigned short* __restrict__ wb) {
    int i = blockIdx.x * 256 + threadIdx.x;     // 73728 = 9*8*4*256
    int j = i & 7;
    int k = (i >> 3) & 31;
    int q = (i >> 8) & 3;
    int ch = (i >> 10) & 7;
    int t = i >> 13;
    int c = (ch << 5) + (q << 3) + j;
    wb[i] = f2bf(w[k * 2304 + c * 9 + t]);
}

// ---------- generic 256x256 weight pack (row stride in floats) ----------
__global__ __launch_bounds__(256) void k_wpack2(const float* __restrict__ w, int stride,
                                                unsigned short* __restrict__ wb) {
    int i = blockIdx.x * 256 + threadIdx.x;     // 65536
    int co = i >> 8, ci = i & 255;
    wb[i] = f2bf(w[(size_t)co * stride + ci]);
}

// ---------- K3: double-buffered MFMA 3x3 conv + fused softmax ----------
// Round-5 change (ONE variable): px-split 64 -> 32 per block. Grid 1024 -> 2048
// (8 blocks/CU), block 128 threads (2 waves), LDS 16.3 KB. Rationale: r4 showed
// all pipes <6% at 4 blocks/CU -- each block is a serial chunk chain with an
// embedded load-latency bubble and nothing co-resident to fill it. Doubling
// independent chains/CU + halving barrier scope attacks exactly that. Halo
// staging rises (34 vs 66 for 32 vs 64 px) -- HBM-insensitive per r3 proof.
// Weight path (r4 repack + batched loads), XCD swizzle, epilogue unchanged.
__global__ __launch_bounds__(128, 4) void k_conv(
    const unsigned short* __restrict__ xnb, const unsigned short* __restrict__ wb,
    const float* __restrict__ bias, float* __restrict__ sa)
{
    __shared__ __align__(16) unsigned short lsB[2][3 * 34 * 40];   // 2 x 8160 B
    int bid = blockIdx.x;                       // 2048 = px_b(2) x y(64) x n(16)
    int n = bid & 15, y = (bid >> 4) & 63, px_b = bid >> 10;   // XCD swizzle: n%8 = XCD
    int tid = threadIdx.x;
    int wv = tid >> 6, lane = tid & 63;
    int r = lane & 15, quad = lane >> 4;
    int pxw = (wv << 4) + r;                    // block-local out x (0..31)
    int xbase = (px_b << 5) - 1;                // input col of stored idx 0
    const unsigned short* xb = xnb + (size_t)n * CL_;

    // staging plan: 3 rows x 34 px x 4 quads = 408 uint4 items, 3-4 per thread
    const unsigned short* sptr[4];
    int sidx[4];
    bool svalid[4];
    int scnt = (tid < 24) ? 4 : 3;
#pragma unroll
    for (int k = 0; k < 4; ++k) {
        int j = tid + (k << 7);
        int row = j / 136; if (row > 2) row = 2;
        int rem = j - row * 136;
        int px = rem >> 2, q = rem & 3;
        int yy = y + row - 1, xx = xbase + px;
        bool ok = ((unsigned)yy < 64u) && ((unsigned)xx < 64u);
        int yc = ok ? yy : 0, xc = ok ? xx : 0;
        sptr[k] = xb + (((size_t)(yc << 6) + xc) << 8) + (q << 3);
        svalid[k] = ok;
        sidx[k] = (row * 34 + px) * 40 + (q << 3);
    }
    const uint4 z4 = make_uint4(0, 0, 0, 0);
    uint4 pre[4];
#pragma unroll
    for (int k = 0; k < 4; ++k)
        pre[k] = (k < scnt && svalid[k]) ? *(const uint4*)sptr[k] : z4;

    // wave-invariant weight base for this lane: + r*8 within each 256-short panel
    const unsigned short* wlane = wb + (quad << 8) + (r << 3);

    f32x4 acc0 = (f32x4){0.f, 0.f, 0.f, 0.f};
    f32x4 acc1 = (f32x4){0.f, 0.f, 0.f, 0.f};
    for (int i = 0; i < 8; ++i) {
        int c0 = i << 5;
        unsigned short* buf = lsB[i & 1];
#pragma unroll
        for (int k = 0; k < 4; ++k)
            if (k < scnt) *(uint4*)(buf + sidx[k]) = pre[k];
        __syncthreads();                        // single barrier/chunk (2-wave scope)
        if (i < 7) {
#pragma unroll
            for (int k = 0; k < 4; ++k)
                pre[k] = (k < scnt && svalid[k]) ? *(const uint4*)(sptr[k] + c0 + 32) : z4;
        }
        // panel index for (t, chunk i): ((t*8 + i)*4 + quad)*256
#pragma unroll
        for (int dy = 0; dy < 3; ++dy) {
            short8 A0r[3], A1r[3], Br[3];
#pragma unroll
            for (int dx = 0; dx < 3; ++dx) {
                int t = dy * 3 + dx;
                const unsigned short* wp = wlane + (((t << 3) + i) << 10);  // (t*8+i)*4*256
                A0r[dx] = *(const short8*)wp;             // k = r
                A1r[dx] = *(const short8*)(wp + 128);     // k = 16 + r
                Br[dx]  = *(const short8*)(buf + (dy * 34 + pxw + dx) * 40 + (quad << 3));
            }
#pragma unroll
            for (int dx = 0; dx < 3; ++dx) {
                acc0 = __builtin_amdgcn_mfma_f32_16x16x32_bf16(A0r[dx], Br[dx], acc0, 0, 0, 0);
                acc1 = __builtin_amdgcn_mfma_f32_16x16x32_bf16(A1r[dx], Br[dx], acc1, 0, 0, 0);
            }
        }
    }
    // bias + softmax over k (32 values per px: 4 quads x 8 regs)
    float4 b0 = *(const float4*)(bias + (quad << 2));
    float4 b1 = *(const float4*)(bias + 16 + (quad << 2));
    float v[8];
    v[0] = acc0[0] + b0.x; v[1] = acc0[1] + b0.y; v[2] = acc0[2] + b0.z; v[3] = acc0[3] + b0.w;
    v[4] = acc1[0] + b1.x; v[5] = acc1[1] + b1.y; v[6] = acc1[2] + b1.z; v[7] = acc1[3] + b1.w;
    float mx = v[0];
#pragma unroll
    for (int j = 1; j < 8; ++j) mx = fmaxf(mx, v[j]);
    mx = fmaxf(mx, __shfl_xor(mx, 16));
    mx = fmaxf(mx, __shfl_xor(mx, 32));
    float s = 0.f;
#pragma unroll
    for (int j = 0; j < 8; ++j) { v[j] = __expf(v[j] - mx); s += v[j]; }
    s += __shfl_xor(s, 16);
    s += __shfl_xor(s, 32);
    float rs = 1.0f / s;
    int l = (y << 6) + (px_b << 5) + pxw;
    float* sp = sa + (size_t)n * KL_ + l;
#pragma unroll
    for (int j = 0; j < 4; ++j) {
        sp[(size_t)((quad << 2) + j) * L_] = v[j] * rs;
        sp[(size_t)(16 + (quad << 2) + j) * L_] = v[4 + j] * rs;
    }
}

// ---------- K4: ssum[n,k] = sum_l sa[n,k,l] ----------
__global__ __launch_bounds__(256) void k_ssum(const float* __restrict__ sa, float* __restrict__ ssum) {
    __shared__ float red[256];
    int bid = blockIdx.x;                       // n*K + k
    const float* sp = sa + (size_t)bid * L_;
    float s = 0.f;
    for (int m = 0; m < 16; ++m) s += sp[threadIdx.x + (m << 8)];
    red[threadIdx.x] = s; __syncthreads();
    for (int st = 128; st > 0; st >>= 1) {
        if (threadIdx.x < st) red[threadIdx.x] += red[threadIdx.x + st];
        __syncthreads();
    }
    if (threadIdx.x == 0) ssum[bid] = red[0];
}

// ---------- K5: up[n,k,c] += sum_l sa[n,k,l] * xn[n,c,l] ----------
__global__ __launch_bounds__(256) void k_einsum(
    const float* __restrict__ f, const float* __restrict__ rinv,
    const float* __restrict__ sa, float* __restrict__ up)
{
    __shared__ float xn_s[C_ * 33];
    __shared__ float sa_s[K_ * 32];
    int bid = blockIdx.x;                       // 512
    int n = bid >> 5;
    int l0 = (bid & 31) << 7;
    int tid = threadIdx.x;
    int kq = tid >> 5, cq = tid & 31;
    float acc[4][8];
#pragma unroll
    for (int i = 0; i < 4; ++i)
#pragma unroll
        for (int j = 0; j < 8; ++j) acc[i][j] = 0.f;

    for (int ch = 0; ch < 4; ++ch) {
        int lc = l0 + (ch << 5);
        __syncthreads();
        {
            int crow = tid >> 3, lq = (tid & 7) << 2;
#pragma unroll
            for (int p = 0; p < 8; ++p) {
                int c = (p << 5) + crow;
                float4 f4 = *(const float4*)(f + (size_t)n * CL_ + (size_t)c * L_ + lc + lq);
                float4 r4 = *(const float4*)(rinv + n * L_ + lc + lq);
                float* d = xn_s + c * 33 + lq;
                d[0] = f4.x * r4.x; d[1] = f4.y * r4.y; d[2] = f4.z * r4.z; d[3] = f4.w * r4.w;
            }
        }
        {
            int k = tid >> 3, lq = (tid & 7) << 2;
            float4 a4 = *(const float4*)(sa + (size_t)n * KL_ + (size_t)k * L_ + lc + lq);
            *(float4*)(sa_s + (k << 5) + lq) = a4;
        }
        __syncthreads();
#pragma unroll 4
        for (int l = 0; l < 32; ++l) {
            float sv[4], xv[8];
#pragma unroll
            for (int i = 0; i < 4; ++i) sv[i] = sa_s[((kq << 2) + i) * 32 + l];
#pragma unroll
            for (int j = 0; j < 8; ++j) xv[j] = xn_s[(cq + (j << 5)) * 33 + l];
#pragma unroll
            for (int i = 0; i < 4; ++i)
#pragma unroll
                for (int j = 0; j < 8; ++j) acc[i][j] = fmaf(sv[i], xv[j], acc[i][j]);
        }
    }
    float* upp = up + (size_t)n * KC_;
#pragma unroll
    for (int i = 0; i < 4; ++i)
#pragma unroll
        for (int j = 0; j < 8; ++j)
            atomicAdd(upp + ((kq << 2) + i) * C_ + cq + (j << 5), acc[i][j]);
}

// ---------- K6: subtract centroid term, l2norm rows, record row sumsq ----------
__global__ __launch_bounds__(256) void k_rowfix(
    const float* __restrict__ up, const float* __restrict__ ssum,
    const float* __restrict__ cent, float* __restrict__ upn, float* __restrict__ rowss)
{
    __shared__ float red[256];
    int bid = blockIdx.x;                       // n*K + k
    int k = bid & 31;
    float sv = ssum[bid];
    float v = up[(size_t)bid * C_ + threadIdx.x] - sv * cent[k * C_ + threadIdx.x];
    red[threadIdx.x] = v * v; __syncthreads();
    for (int st = 128; st > 0; st >>= 1) {
        if (threadIdx.x < st) red[threadIdx.x] += red[threadIdx.x + st];
        __syncthreads();
    }
    float ss = red[0];
    float ri = 1.0f / fmaxf(sqrtf(ss), 1e-12f);
    upn[(size_t)bid * C_ + threadIdx.x] = v * ri;
    if (threadIdx.x == 0) rowss[bid] = ss * ri * ri;
}

// ---------- K7: global l2norm + FC, one block per output channel c ----------
__global__ __launch_bounds__(256) void k_fc(
    const float* __restrict__ upn, const float* __restrict__ rowss,
    const float* __restrict__ w, const float* __restrict__ b,
    float* __restrict__ upvec)
{
    __shared__ float rnb[16];
    __shared__ float red[16][5];
    int c = blockIdx.x;                         // 256
    int tid = threadIdx.x;
    int wv = tid >> 6, lane = tid & 63;
    if (tid < 16) {
        float ts = 0.f;
#pragma unroll
        for (int k = 0; k < K_; ++k) ts += rowss[(tid << 5) + k];
        rnb[tid] = 1.0f / fmaxf(sqrtf(ts), 1e-12f);
    }
    float acc[16];
#pragma unroll
    for (int n = 0; n < 16; ++n) acc[n] = 0.f;
    const float* wr = w + (size_t)c * KC_;
#pragma unroll
    for (int g = 0; g < 8; ++g) {
        int kc = (g << 10) + (tid << 2);
        float4 w4 = *(const float4*)(wr + kc);
#pragma unroll
        for (int n = 0; n < 16; ++n) {
            float4 u4 = *(const float4*)(upn + n * KC_ + kc);
            acc[n] += w4.x * u4.x + w4.y * u4.y + w4.z * u4.z + w4.w * u4.w;
        }
    }
#pragma unroll
    for (int n = 0; n < 16; ++n) {
        float a = acc[n];
#pragma unroll
        for (int s = 1; s < 64; s <<= 1) a += __shfl_xor(a, s);
        if (lane == 0) red[n][wv] = a;
    }
    __syncthreads();
    if (tid < 16) {
        float v = red[tid][0] + red[tid][1] + red[tid][2] + red[tid][3];
        upvec[tid * C_ + c] = v * rnb[tid] + b[c];
    }
}

// ---------- K8: t1up[n,co] = t1_w[co,256:512] . upvec[n,:] + t1_b[co] ----------
__global__ __launch_bounds__(256) void k_t1up(
    const float* __restrict__ upvec, const float* __restrict__ t1w,
    const float* __restrict__ t1b, float* __restrict__ t1up)
{
    __shared__ float wld[256];
    int co = blockIdx.x;                        // 256
    int tid = threadIdx.x;
    wld[tid] = t1w[(size_t)co * 512 + 256 + tid];
    __syncthreads();
    int n = tid >> 4, s = tid & 15;
    float a = 0.f;
#pragma unroll
    for (int i = 0; i < 16; ++i)
        a += wld[s + (i << 4)] * upvec[n * C_ + s + (i << 4)];
#pragma unroll
    for (int st = 1; st < 16; st <<= 1) a += __shfl_xor(a, st);
    if (s == 0) t1up[n * C_ + co] = a + t1b[co];
}

// ---------- K9: MFMA gemm1, pipelined LDS-staged B from fp32 feature ----------
// hb[n,l,co] = bf16(relu(f[n,:,l]·t1wb[co,:] + t1up[n,co]))
__global__ __launch_bounds__(256) void k_gemm1(
    const float* __restrict__ f, const unsigned short* __restrict__ wb,
    const float* __restrict__ t1up, unsigned short* __restrict__ hb)
{
    __shared__ __align__(16) unsigned int lsB[2][128 * 20];     // px stride 20 uints (padded)
    int bid = blockIdx.x;                       // 1024 = n(16) x px_b(32) x co_b(2)
    int co_b = bid & 1, px_b = (bid >> 1) & 31, n = bid >> 6;
    int l0 = px_b << 7;
    int tid = threadIdx.x;
    int wv = tid >> 6, lane = tid & 63;
    int r = lane & 15, quad = lane >> 4;
    int pxl = (wv >> 1) << 6;                   // block-local px base for wave
    int co0 = (co_b << 7) + ((wv & 1) << 6);
    const float* fb_ = f + (size_t)n * CL_ + l0;
    int c2 = tid & 15, pxg = tid >> 4;          // item 0; item 1 = +256 -> pxg+16

    unsigned int pk[2][4];
#pragma unroll
    for (int k2 = 0; k2 < 2; ++k2) {
        const float* s0 = fb_ + (size_t)(c2 << 1) * L_ + ((pxg + (k2 << 4)) << 2);
        float4 a = *(const float4*)s0;
        float4 b = *(const float4*)(s0 + L_);
        pk[k2][0] = pack2(a.x, b.x); pk[k2][1] = pack2(a.y, b.y);
        pk[k2][2] = pack2(a.z, b.z); pk[k2][3] = pack2(a.w, b.w);
    }
    f32x4 acc[4][4];
#pragma unroll
    for (int i = 0; i < 4; ++i)
#pragma unroll
        for (int j = 0; j < 4; ++j) acc[i][j] = (f32x4){0.f, 0.f, 0.f, 0.f};

    for (int i = 0; i < 8; ++i) {
        int c0 = i << 5;
        unsigned int* buf = lsB[i & 1];
#pragma unroll
        for (int k2 = 0; k2 < 2; ++k2) {
            int base = (pxg + (k2 << 4)) * 80 + c2;     // 4 px * 20-uint stride
            buf[base]      = pk[k2][0];
            buf[base + 20] = pk[k2][1];
            buf[base + 40] = pk[k2][2];
            buf[base + 60] = pk[k2][3];
        }
        __syncthreads();
        if (i < 7) {
#pragma unroll
            for (int k2 = 0; k2 < 2; ++k2) {
                const float* s0 = fb_ + (size_t)(c0 + 32 + (c2 << 1)) * L_ + ((pxg + (k2 << 4)) << 2);
                float4 a = *(const float4*)s0;
                float4 b = *(const float4*)(s0 + L_);
                pk[k2][0] = pack2(a.x, b.x); pk[k2][1] = pack2(a.y, b.y);
                pk[k2][2] = pack2(a.z, b.z); pk[k2][3] = pack2(a.w, b.w);
            }
        }
        short8 A[4], B[4];
#pragma unroll
        for (int t = 0; t < 4; ++t)
            A[t] = *(const short8*)(wb + (size_t)(co0 + (t << 4) + r) * C_ + c0 + (quad << 3));
#pragma unroll
        for (int t = 0; t < 4; ++t)
            B[t] = *(const short8*)((const unsigned short*)buf + (pxl + (t << 4) + r) * 40 + (quad << 3));
#pragma unroll
        for (int pxt = 0; pxt < 4; ++pxt)
#pragma unroll
            for (int cot = 0; cot < 4; ++cot)
                acc[pxt][cot] = __builtin_amdgcn_mfma_f32_16x16x32_bf16(A[cot], B[pxt], acc[pxt][cot], 0, 0, 0);
    }
#pragma unroll
    for (int pxt = 0; pxt < 4; ++pxt) {
        int px = l0 + pxl + (pxt << 4) + r;
        unsigned short* orow = hb + ((size_t)n * L_ + px) * C_;
#pragma unroll
        for (int cot = 0; cot < 4; ++cot) {
            int cb = co0 + (cot << 4) + (quad << 2);
            float4 bb = *(const float4*)(t1up + n * C_ + cb);
            unsigned int p0 = pack2(fmaxf(acc[pxt][cot][0] + bb.x, 0.f),
                                    fmaxf(acc[pxt][cot][1] + bb.y, 0.f));
            unsigned int p1 = pack2(fmaxf(acc[pxt][cot][2] + bb.z, 0.f),
                                    fmaxf(acc[pxt][cot][3] + bb.w, 0.f));
            *(uint2*)(orow + cb) = make_uint2(p0, p1);
        }
    }
}

// ---------- K10: MFMA gemm2, pipelined LDS-staged B from hb ----------
// out[n,co,l] = relu(hb[n,l,:]·t2wb[co,:] + t2b[co])
__global__ __launch_bounds__(256) void k_gemm2(
    const unsigned short* __restrict__ hb, const unsigned short* __restrict__ wb,
    const float* __restrict__ t2b, float* __restrict__ out)
{
    __shared__ __align__(16) unsigned short lsB[2][128 * 40];   // px stride 40 ushorts (padded)
    int bid = blockIdx.x;                       // 1024
    int co_b = bid & 1, px_b = (bid >> 1) & 31, n = bid >> 6;
    int l0 = px_b << 7;
    int tid = threadIdx.x;
    int wv = tid >> 6, lane = tid & 63;
    int r = lane & 15, quad = lane >> 4;
    int pxl = (wv >> 1) << 6;
    int co0 = (co_b << 7) + ((wv & 1) << 6);
    const unsigned short* hrow = hb + ((size_t)n * L_ + l0) * C_;
    int q = tid & 3, pxs = tid >> 2;            // item 0: px = pxs; item 1: px = pxs+64

    uint4 pre[2];
#pragma unroll
    for (int k2 = 0; k2 < 2; ++k2)
        pre[k2] = *(const uint4*)(hrow + (size_t)(pxs + (k2 << 6)) * C_ + (q << 3));

    f32x4 acc[4][4];
#pragma unroll
    for (int i = 0; i < 4; ++i)
#pragma unroll
        for (int j = 0; j < 4; ++j) acc[i][j] = (f32x4){0.f, 0.f, 0.f, 0.f};

    for (int i = 0; i < 8; ++i) {
        int c0 = i << 5;
        unsigned short* buf = lsB[i & 1];
#pragma unroll
        for (int k2 = 0; k2 < 2; ++k2)
            *(uint4*)(buf + (pxs + (k2 << 6)) * 40 + (q << 3)) = pre[k2];
        __syncthreads();
        if (i < 7) {
#pragma unroll
            for (int k2 = 0; k2 < 2; ++k2)
                pre[k2] = *(const uint4*)(hrow + (size_t)(pxs + (k2 << 6)) * C_ + c0 + 32 + (q << 3));
        }
        short8 A[4], B[4];
#pragma unroll
        for (int t = 0; t < 4; ++t)
            A[t] = *(const short8*)(wb + (size_t)(co0 + (t << 4) + r) * C_ + c0 + (quad << 3));
#pragma unroll
        for (int t = 0; t < 4; ++t)
            B[t] = *(const short8*)(buf + (pxl + (t << 4) + r) * 40 + (quad << 3));
#pragma unroll
        for (int pxt = 0; pxt < 4; ++pxt)
#pragma unroll
            for (int cot = 0; cot < 4; ++cot)
                acc[pxt][cot] = __builtin_amdgcn_mfma_f32_16x16x32_bf16(A[cot], B[pxt], acc[pxt][cot], 0, 0, 0);
    }
#pragma unroll
    for (int pxt = 0; pxt < 4; ++pxt) {
        int px = l0 + pxl + (pxt << 4) + r;
#pragma unroll
        for (int cot = 0; cot < 4; ++cot) {
            int cb = co0 + (cot << 4) + (quad << 2);
            float4 bb = *(const float4*)(t2b + cb);
            out[((size_t)n * C_ + cb + 0) * L_ + px] = fmaxf(acc[pxt][cot][0] + bb.x, 0.f);
            out[((size_t)n * C_ + cb + 1) * L_ + px] = fmaxf(acc[pxt][cot][1] + bb.y, 0.f);
            out[((size_t)n * C_ + cb + 2) * L_ + px] = fmaxf(acc[pxt][cot][2] + bb.z, 0.f);
            out[((size_t)n * C_ + cb + 3) * L_ + px] = fmaxf(acc[pxt][cot][3] + bb.w, 0.f);
        }
    }
}

extern "C" void kernel_launch(void* const* d_in, const int* in_sizes, int n_in,
                              void* d_out, int out_size, void* d_ws, size_t ws_size,
                              hipStream_t stream)
{
    const float* feature = (const float*)d_in[0];
    const float* conv_w  = (const float*)d_in[1];
    const float* conv_b  = (const float*)d_in[2];
    const float* cent    = (const float*)d_in[3];
    const float* upfc_w  = (const float*)d_in[4];
    const float* upfc_b  = (const float*)d_in[5];
    const float* t1w     = (const float*)d_in[6];
    const float* t1b     = (const float*)d_in[7];
    const float* t2w     = (const float*)d_in[8];
    const float* t2b     = (const float*)d_in[9];

    float* ws = (float*)d_ws;                    // 43.3 MB total
    unsigned short* xnb = (unsigned short*)ws;           // 16777216 us (32 MB)
    unsigned short* hb  = xnb;                           // alias: xnb dead after k_conv
    float* rest  = ws + 8388608;
    float* rinv  = rest;                         // 65536
    float* sa    = rinv + 65536;                 // 2097152 (8 MB)
    float* up    = sa + 2097152;                 // 131072
    float* ssum  = up + 131072;                  // 512
    float* upn   = ssum + 512;                   // 131072
    float* rowss = upn + 131072;                 // 512
    float* upvec = rowss + 512;                  // 4096
    float* t1up  = upvec + 4096;                 // 4096
    unsigned short* wbconv = (unsigned short*)upn;       // alias: upn written later by k_rowfix
    unsigned short* t1wb = (unsigned short*)sa;          // alias: sa dead after k_einsum
    unsigned short* t2wb = t1wb + 65536;
    float* out = (float*)d_out;

    hipMemsetAsync(up, 0, 131072 * sizeof(float), stream);
    k_prep     <<<2048, 256, 0, stream>>>(feature, rinv, xnb);
    k_wpack    <<<288,  256, 0, stream>>>(conv_w, wbconv);
    k_conv     <<<2048, 128, 0, stream>>>(xnb, wbconv, conv_b, sa);
    k_ssum     <<<512,  256, 0, stream>>>(sa, ssum);
    k_einsum   <<<512,  256, 0, stream>>>(feature, rinv, sa, up);
    k_rowfix   <<<512,  256, 0, stream>>>(up, ssum, cent, upn, rowss);
    k_wpack2   <<<256,  256, 0, stream>>>(t1w, 512, t1wb);
    k_wpack2   <<<256,  256, 0, stream>>>(t2w, 256, t2wb);
    k_fc       <<<256,  256, 0, stream>>>(upn, rowss, upfc_w, upfc_b, upvec);
    k_t1up     <<<256,  256, 0, stream>>>(upvec, t1w, t1b, t1up);
    k_gemm1    <<<1024, 256, 0, stream>>>(feature, t1wb, t1up, hb);
    k_gemm2    <<<1024, 256, 0, stream>>>(hb, t2wb, t2b, out);
}

// Round 6
// 337.012 us; speedup vs baseline: 1.0159x; 1.0159x over previous
//
#include <hip/hip_runtime.h>
#include <cstdint>

#define N_ 16
#define C_ 256
#define H_ 64
#define W_ 64
#define L_ 4096          // H*W
#define K_ 32
#define CL_ (C_*L_)      // 1048576
#define KL_ (K_*L_)      // 131072
#define KC_ (K_*C_)      // 8192

typedef __attribute__((ext_vector_type(8))) short short8;   // 8 bf16 (4 VGPRs)
typedef __attribute__((ext_vector_type(4))) float f32x4;    // MFMA C/D frag

__device__ __forceinline__ unsigned short f2bf(float x) {   // RNE fp32->bf16
    unsigned int u = __float_as_uint(x);
    u += 0x7fffu + ((u >> 16) & 1u);
    return (unsigned short)(u >> 16);
}
__device__ __forceinline__ unsigned int pack2(float a, float b) {
    return (unsigned int)f2bf(a) | ((unsigned int)f2bf(b) << 16);
}

// ---------- K1: fused rinv + xn(bf16) transposed to (n,l,c) ----------
__global__ __launch_bounds__(256) void k_prep(
    const float* __restrict__ f, float* __restrict__ rinv,
    unsigned short* __restrict__ xnb)
{
    __shared__ float tile[256 * 34];            // [c][l], stride 34 (conflict-free)
    __shared__ float ssred[8 * 33];
    __shared__ float rbuf[32];
    int bid = blockIdx.x;
    int n = bid >> 7;
    int l0 = (bid & 127) << 5;
    int tid = threadIdx.x;
    int l = tid & 31, cb = tid >> 5;            // cb 0..7
    const float* fp = f + (size_t)n * CL_ + l0 + l;
    float ss = 0.f;
#pragma unroll
    for (int i = 0; i < 32; ++i) {
        int c = (cb << 5) + i;
        float v = fp[(size_t)c * L_];
        tile[c * 34 + l] = v;
        ss = fmaf(v, v, ss);
    }
    ssred[cb * 33 + l] = ss;
    __syncthreads();
    if (tid < 32) {
        float s = 0.f;
#pragma unroll
        for (int j = 0; j < 8; ++j) s += ssred[j * 33 + tid];
        float ri = 1.0f / fmaxf(sqrtf(s), 1e-12f);
        rinv[n * L_ + l0 + tid] = ri;
        rbuf[tid] = ri;
    }
    __syncthreads();
    float ri = rbuf[l];
    unsigned short* op = xnb + ((size_t)n * L_ + l0 + l) * C_ + (cb << 5);
#pragma unroll
    for (int g = 0; g < 4; ++g) {
        unsigned int pk[4];
#pragma unroll
        for (int d = 0; d < 4; ++d) {
            int c = (cb << 5) + (g << 3) + (d << 1);
            pk[d] = pack2(tile[c * 34 + l] * ri, tile[(c + 1) * 34 + l] * ri);
        }
        *(uint4*)(op + (g << 3)) = make_uint4(pk[0], pk[1], pk[2], pk[3]);
    }
}

// ---------- K2: repack conv weights -> wb[t][ch][q][k][8] bf16 ----------
// linear = ((t*8 + ch)*4 + q)*256 + k*8 + j, with c = ch*32+q*8+j.
// A-fragment load for lane (r,quad): wb + ((t*8+ch)*4+quad)*256 + r*8 ->
// consecutive r lanes CONTIGUOUS 16B -> 4x256B segments per instruction.
__global__ __launch_bounds__(256) void k_wpack(const float* __restrict__ w, unsigned short* __restrict__ wb) {
    int i = blockIdx.x * 256 + threadIdx.x;     // 73728 = 9*8*4*256
    int j = i & 7;
    int k = (i >> 3) & 31;
    int q = (i >> 8) & 3;
    int ch = (i >> 10) & 7;
    int t = i >> 13;
    int c = (ch << 5) + (q << 3) + j;
    wb[i] = f2bf(w[k * 2304 + c * 9 + t]);
}

// ---------- generic 256x256 weight pack (row stride in floats) ----------
__global__ __launch_bounds__(256) void k_wpack2(const float* __restrict__ w, int stride,
                                                unsigned short* __restrict__ wb) {
    int i = blockIdx.x * 256 + threadIdx.x;     // 65536
    int co = i >> 8, ci = i & 255;
    wb[i] = f2bf(w[(size_t)co * stride + ci]);
}

// ---------- K3: double-buffered MFMA 3x3 conv + fused softmax + fused ssum ----------
// Round-6 change (ONE variable on the spill): __launch_bounds__(128, 2) -> VGPR
// budget 256 (was 128 w/ min-4-waves). r4/r5's batch arrays spilled in-loop at
// VGPR_Count 52 (WRITE_SIZE 98-106 MB phantom writes = scratch). r5 proved extra
// blocks/CU are worthless (2x blocks -> dur unchanged), so the occupancy cap
// from min=2 costs nothing. Expect VGPR ~110, WRITE ~13 MB, dur 62 -> ~48.
// Also: ssum fused into epilogue (post-loop, tiny state, proven in r1/r2),
// k_ssum kernel deleted.
__global__ __launch_bounds__(128, 2) void k_conv(
    const unsigned short* __restrict__ xnb, const unsigned short* __restrict__ wb,
    const float* __restrict__ bias, float* __restrict__ sa, float* __restrict__ ssum)
{
    __shared__ __align__(16) unsigned short lsB[2][3 * 34 * 40];   // 2 x 8160 B
    __shared__ float sred[2][32];
    int bid = blockIdx.x;                       // 2048 = px_b(2) x y(64) x n(16)
    int n = bid & 15, y = (bid >> 4) & 63, px_b = bid >> 10;   // XCD swizzle: n%8 = XCD
    int tid = threadIdx.x;
    int wv = tid >> 6, lane = tid & 63;
    int r = lane & 15, quad = lane >> 4;
    int pxw = (wv << 4) + r;                    // block-local out x (0..31)
    int xbase = (px_b << 5) - 1;                // input col of stored idx 0
    const unsigned short* xb = xnb + (size_t)n * CL_;

    // staging plan: 3 rows x 34 px x 4 quads = 408 uint4 items, 3-4 per thread
    const unsigned short* sptr[4];
    int sidx[4];
    bool svalid[4];
    int scnt = (tid < 24) ? 4 : 3;
#pragma unroll
    for (int k = 0; k < 4; ++k) {
        int j = tid + (k << 7);
        int row = j / 136; if (row > 2) row = 2;
        int rem = j - row * 136;
        int px = rem >> 2, q = rem & 3;
        int yy = y + row - 1, xx = xbase + px;
        bool ok = ((unsigned)yy < 64u) && ((unsigned)xx < 64u);
        int yc = ok ? yy : 0, xc = ok ? xx : 0;
        sptr[k] = xb + (((size_t)(yc << 6) + xc) << 8) + (q << 3);
        svalid[k] = ok;
        sidx[k] = (row * 34 + px) * 40 + (q << 3);
    }
    const uint4 z4 = make_uint4(0, 0, 0, 0);
    uint4 pre[4];
#pragma unroll
    for (int k = 0; k < 4; ++k)
        pre[k] = (k < scnt && svalid[k]) ? *(const uint4*)sptr[k] : z4;

    // wave-invariant weight base for this lane: + r*8 within each 256-short panel
    const unsigned short* wlane = wb + (quad << 8) + (r << 3);

    f32x4 acc0 = (f32x4){0.f, 0.f, 0.f, 0.f};
    f32x4 acc1 = (f32x4){0.f, 0.f, 0.f, 0.f};
    for (int i = 0; i < 8; ++i) {
        int c0 = i << 5;
        unsigned short* buf = lsB[i & 1];
#pragma unroll
        for (int k = 0; k < 4; ++k)
            if (k < scnt) *(uint4*)(buf + sidx[k]) = pre[k];
        __syncthreads();                        // single barrier/chunk (2-wave scope)
        if (i < 7) {
#pragma unroll
            for (int k = 0; k < 4; ++k)
                pre[k] = (k < scnt && svalid[k]) ? *(const uint4*)(sptr[k] + c0 + 32) : z4;
        }
        // panel index for (t, chunk i): ((t*8 + i)*4 + quad)*256
#pragma unroll
        for (int dy = 0; dy < 3; ++dy) {
            short8 A0r[3], A1r[3], Br[3];
#pragma unroll
            for (int dx = 0; dx < 3; ++dx) {
                int t = dy * 3 + dx;
                const unsigned short* wp = wlane + (((t << 3) + i) << 10);  // (t*8+i)*4*256
                A0r[dx] = *(const short8*)wp;             // k = r
                A1r[dx] = *(const short8*)(wp + 128);     // k = 16 + r
                Br[dx]  = *(const short8*)(buf + (dy * 34 + pxw + dx) * 40 + (quad << 3));
            }
#pragma unroll
            for (int dx = 0; dx < 3; ++dx) {
                acc0 = __builtin_amdgcn_mfma_f32_16x16x32_bf16(A0r[dx], Br[dx], acc0, 0, 0, 0);
                acc1 = __builtin_amdgcn_mfma_f32_16x16x32_bf16(A1r[dx], Br[dx], acc1, 0, 0, 0);
            }
        }
    }
    // bias + softmax over k (32 values per px: 4 quads x 8 regs)
    float4 b0 = *(const float4*)(bias + (quad << 2));
    float4 b1 = *(const float4*)(bias + 16 + (quad << 2));
    float v[8];
    v[0] = acc0[0] + b0.x; v[1] = acc0[1] + b0.y; v[2] = acc0[2] + b0.z; v[3] = acc0[3] + b0.w;
    v[4] = acc1[0] + b1.x; v[5] = acc1[1] + b1.y; v[6] = acc1[2] + b1.z; v[7] = acc1[3] + b1.w;
    float mx = v[0];
#pragma unroll
    for (int j = 1; j < 8; ++j) mx = fmaxf(mx, v[j]);
    mx = fmaxf(mx, __shfl_xor(mx, 16));
    mx = fmaxf(mx, __shfl_xor(mx, 32));
    float s = 0.f;
#pragma unroll
    for (int j = 0; j < 8; ++j) { v[j] = __expf(v[j] - mx); s += v[j]; }
    s += __shfl_xor(s, 16);
    s += __shfl_xor(s, 32);
    float rs = 1.0f / s;
    float sv8[8];
#pragma unroll
    for (int j = 0; j < 8; ++j) sv8[j] = v[j] * rs;
    int l = (y << 6) + (px_b << 5) + pxw;
    float* sp = sa + (size_t)n * KL_ + l;
#pragma unroll
    for (int j = 0; j < 4; ++j) {
        sp[(size_t)((quad << 2) + j) * L_] = sv8[j];
        sp[(size_t)(16 + (quad << 2) + j) * L_] = sv8[4 + j];
    }
    // fused ssum: reduce over this wave's 16 px (lane bits 0-3), combine 2 waves
#pragma unroll
    for (int j = 0; j < 8; ++j) {
        float a = sv8[j];
        a += __shfl_xor(a, 1); a += __shfl_xor(a, 2);
        a += __shfl_xor(a, 4); a += __shfl_xor(a, 8);
        sv8[j] = a;
    }
    if (r == 0) {
#pragma unroll
        for (int j = 0; j < 4; ++j) {
            sred[wv][(quad << 2) + j] = sv8[j];
            sred[wv][16 + (quad << 2) + j] = sv8[4 + j];
        }
    }
    __syncthreads();
    if (tid < 32) {
        float t = sred[0][tid] + sred[1][tid];
        atomicAdd(ssum + n * K_ + tid, t);
    }
}

// ---------- K5: up[n,k,c] += sum_l sa[n,k,l] * xn[n,c,l] ----------
__global__ __launch_bounds__(256) void k_einsum(
    const float* __restrict__ f, const float* __restrict__ rinv,
    const float* __restrict__ sa, float* __restrict__ up)
{
    __shared__ float xn_s[C_ * 33];
    __shared__ float sa_s[K_ * 32];
    int bid = blockIdx.x;                       // 512
    int n = bid >> 5;
    int l0 = (bid & 31) << 7;
    int tid = threadIdx.x;
    int kq = tid >> 5, cq = tid & 31;
    float acc[4][8];
#pragma unroll
    for (int i = 0; i < 4; ++i)
#pragma unroll
        for (int j = 0; j < 8; ++j) acc[i][j] = 0.f;

    for (int ch = 0; ch < 4; ++ch) {
        int lc = l0 + (ch << 5);
        __syncthreads();
        {
            int crow = tid >> 3, lq = (tid & 7) << 2;
#pragma unroll
            for (int p = 0; p < 8; ++p) {
                int c = (p << 5) + crow;
                float4 f4 = *(const float4*)(f + (size_t)n * CL_ + (size_t)c * L_ + lc + lq);
                float4 r4 = *(const float4*)(rinv + n * L_ + lc + lq);
                float* d = xn_s + c * 33 + lq;
                d[0] = f4.x * r4.x; d[1] = f4.y * r4.y; d[2] = f4.z * r4.z; d[3] = f4.w * r4.w;
            }
        }
        {
            int k = tid >> 3, lq = (tid & 7) << 2;
            float4 a4 = *(const float4*)(sa + (size_t)n * KL_ + (size_t)k * L_ + lc + lq);
            *(float4*)(sa_s + (k << 5) + lq) = a4;
        }
        __syncthreads();
#pragma unroll 4
        for (int l = 0; l < 32; ++l) {
            float sv[4], xv[8];
#pragma unroll
            for (int i = 0; i < 4; ++i) sv[i] = sa_s[((kq << 2) + i) * 32 + l];
#pragma unroll
            for (int j = 0; j < 8; ++j) xv[j] = xn_s[(cq + (j << 5)) * 33 + l];
#pragma unroll
            for (int i = 0; i < 4; ++i)
#pragma unroll
                for (int j = 0; j < 8; ++j) acc[i][j] = fmaf(sv[i], xv[j], acc[i][j]);
        }
    }
    float* upp = up + (size_t)n * KC_;
#pragma unroll
    for (int i = 0; i < 4; ++i)
#pragma unroll
        for (int j = 0; j < 8; ++j)
            atomicAdd(upp + ((kq << 2) + i) * C_ + cq + (j << 5), acc[i][j]);
}

// ---------- K6: subtract centroid term, l2norm rows, record row sumsq ----------
__global__ __launch_bounds__(256) void k_rowfix(
    const float* __restrict__ up, const float* __restrict__ ssum,
    const float* __restrict__ cent, float* __restrict__ upn, float* __restrict__ rowss)
{
    __shared__ float red[256];
    int bid = blockIdx.x;                       // n*K + k
    int k = bid & 31;
    float sv = ssum[bid];
    float v = up[(size_t)bid * C_ + threadIdx.x] - sv * cent[k * C_ + threadIdx.x];
    red[threadIdx.x] = v * v; __syncthreads();
    for (int st = 128; st > 0; st >>= 1) {
        if (threadIdx.x < st) red[threadIdx.x] += red[threadIdx.x + st];
        __syncthreads();
    }
    float ss = red[0];
    float ri = 1.0f / fmaxf(sqrtf(ss), 1e-12f);
    upn[(size_t)bid * C_ + threadIdx.x] = v * ri;
    if (threadIdx.x == 0) rowss[bid] = ss * ri * ri;
}

// ---------- K7: global l2norm + FC, one block per output channel c ----------
__global__ __launch_bounds__(256) void k_fc(
    const float* __restrict__ upn, const float* __restrict__ rowss,
    const float* __restrict__ w, const float* __restrict__ b,
    float* __restrict__ upvec)
{
    __shared__ float rnb[16];
    __shared__ float red[16][5];
    int c = blockIdx.x;                         // 256
    int tid = threadIdx.x;
    int wv = tid >> 6, lane = tid & 63;
    if (tid < 16) {
        float ts = 0.f;
#pragma unroll
        for (int k = 0; k < K_; ++k) ts += rowss[(tid << 5) + k];
        rnb[tid] = 1.0f / fmaxf(sqrtf(ts), 1e-12f);
    }
    float acc[16];
#pragma unroll
    for (int n = 0; n < 16; ++n) acc[n] = 0.f;
    const float* wr = w + (size_t)c * KC_;
#pragma unroll
    for (int g = 0; g < 8; ++g) {
        int kc = (g << 10) + (tid << 2);
        float4 w4 = *(const float4*)(wr + kc);
#pragma unroll
        for (int n = 0; n < 16; ++n) {
            float4 u4 = *(const float4*)(upn + n * KC_ + kc);
            acc[n] += w4.x * u4.x + w4.y * u4.y + w4.z * u4.z + w4.w * u4.w;
        }
    }
#pragma unroll
    for (int n = 0; n < 16; ++n) {
        float a = acc[n];
#pragma unroll
        for (int s = 1; s < 64; s <<= 1) a += __shfl_xor(a, s);
        if (lane == 0) red[n][wv] = a;
    }
    __syncthreads();
    if (tid < 16) {
        float v = red[tid][0] + red[tid][1] + red[tid][2] + red[tid][3];
        upvec[tid * C_ + c] = v * rnb[tid] + b[c];
    }
}

// ---------- K8: t1up[n,co] = t1_w[co,256:512] . upvec[n,:] + t1_b[co] ----------
__global__ __launch_bounds__(256) void k_t1up(
    const float* __restrict__ upvec, const float* __restrict__ t1w,
    const float* __restrict__ t1b, float* __restrict__ t1up)
{
    __shared__ float wld[256];
    int co = blockIdx.x;                        // 256
    int tid = threadIdx.x;
    wld[tid] = t1w[(size_t)co * 512 + 256 + tid];
    __syncthreads();
    int n = tid >> 4, s = tid & 15;
    float a = 0.f;
#pragma unroll
    for (int i = 0; i < 16; ++i)
        a += wld[s + (i << 4)] * upvec[n * C_ + s + (i << 4)];
#pragma unroll
    for (int st = 1; st < 16; st <<= 1) a += __shfl_xor(a, st);
    if (s == 0) t1up[n * C_ + co] = a + t1b[co];
}

// ---------- K9: MFMA gemm1, pipelined LDS-staged B from fp32 feature ----------
// hb[n,l,co] = bf16(relu(f[n,:,l]·t1wb[co,:] + t1up[n,co]))
__global__ __launch_bounds__(256) void k_gemm1(
    const float* __restrict__ f, const unsigned short* __restrict__ wb,
    const float* __restrict__ t1up, unsigned short* __restrict__ hb)
{
    __shared__ __align__(16) unsigned int lsB[2][128 * 20];     // px stride 20 uints (padded)
    int bid = blockIdx.x;                       // 1024 = n(16) x px_b(32) x co_b(2)
    int co_b = bid & 1, px_b = (bid >> 1) & 31, n = bid >> 6;
    int l0 = px_b << 7;
    int tid = threadIdx.x;
    int wv = tid >> 6, lane = tid & 63;
    int r = lane & 15, quad = lane >> 4;
    int pxl = (wv >> 1) << 6;                   // block-local px base for wave
    int co0 = (co_b << 7) + ((wv & 1) << 6);
    const float* fb_ = f + (size_t)n * CL_ + l0;
    int c2 = tid & 15, pxg = tid >> 4;          // item 0; item 1 = +256 -> pxg+16

    unsigned int pk[2][4];
#pragma unroll
    for (int k2 = 0; k2 < 2; ++k2) {
        const float* s0 = fb_ + (size_t)(c2 << 1) * L_ + ((pxg + (k2 << 4)) << 2);
        float4 a = *(const float4*)s0;
        float4 b = *(const float4*)(s0 + L_);
        pk[k2][0] = pack2(a.x, b.x); pk[k2][1] = pack2(a.y, b.y);
        pk[k2][2] = pack2(a.z, b.z); pk[k2][3] = pack2(a.w, b.w);
    }
    f32x4 acc[4][4];
#pragma unroll
    for (int i = 0; i < 4; ++i)
#pragma unroll
        for (int j = 0; j < 4; ++j) acc[i][j] = (f32x4){0.f, 0.f, 0.f, 0.f};

    for (int i = 0; i < 8; ++i) {
        int c0 = i << 5;
        unsigned int* buf = lsB[i & 1];
#pragma unroll
        for (int k2 = 0; k2 < 2; ++k2) {
            int base = (pxg + (k2 << 4)) * 80 + c2;     // 4 px * 20-uint stride
            buf[base]      = pk[k2][0];
            buf[base + 20] = pk[k2][1];
            buf[base + 40] = pk[k2][2];
            buf[base + 60] = pk[k2][3];
        }
        __syncthreads();
        if (i < 7) {
#pragma unroll
            for (int k2 = 0; k2 < 2; ++k2) {
                const float* s0 = fb_ + (size_t)(c0 + 32 + (c2 << 1)) * L_ + ((pxg + (k2 << 4)) << 2);
                float4 a = *(const float4*)s0;
                float4 b = *(const float4*)(s0 + L_);
                pk[k2][0] = pack2(a.x, b.x); pk[k2][1] = pack2(a.y, b.y);
                pk[k2][2] = pack2(a.z, b.z); pk[k2][3] = pack2(a.w, b.w);
            }
        }
        short8 A[4], B[4];
#pragma unroll
        for (int t = 0; t < 4; ++t)
            A[t] = *(const short8*)(wb + (size_t)(co0 + (t << 4) + r) * C_ + c0 + (quad << 3));
#pragma unroll
        for (int t = 0; t < 4; ++t)
            B[t] = *(const short8*)((const unsigned short*)buf + (pxl + (t << 4) + r) * 40 + (quad << 3));
#pragma unroll
        for (int pxt = 0; pxt < 4; ++pxt)
#pragma unroll
            for (int cot = 0; cot < 4; ++cot)
                acc[pxt][cot] = __builtin_amdgcn_mfma_f32_16x16x32_bf16(A[cot], B[pxt], acc[pxt][cot], 0, 0, 0);
    }
#pragma unroll
    for (int pxt = 0; pxt < 4; ++pxt) {
        int px = l0 + pxl + (pxt << 4) + r;
        unsigned short* orow = hb + ((size_t)n * L_ + px) * C_;
#pragma unroll
        for (int cot = 0; cot < 4; ++cot) {
            int cb = co0 + (cot << 4) + (quad << 2);
            float4 bb = *(const float4*)(t1up + n * C_ + cb);
            unsigned int p0 = pack2(fmaxf(acc[pxt][cot][0] + bb.x, 0.f),
                                    fmaxf(acc[pxt][cot][1] + bb.y, 0.f));
            unsigned int p1 = pack2(fmaxf(acc[pxt][cot][2] + bb.z, 0.f),
                                    fmaxf(acc[pxt][cot][3] + bb.w, 0.f));
            *(uint2*)(orow + cb) = make_uint2(p0, p1);
        }
    }
}

// ---------- K10: MFMA gemm2, pipelined LDS-staged B from hb ----------
// out[n,co,l] = relu(hb[n,l,:]·t2wb[co,:] + t2b[co])
__global__ __launch_bounds__(256) void k_gemm2(
    const unsigned short* __restrict__ hb, const unsigned short* __restrict__ wb,
    const float* __restrict__ t2b, float* __restrict__ out)
{
    __shared__ __align__(16) unsigned short lsB[2][128 * 40];   // px stride 40 ushorts (padded)
    int bid = blockIdx.x;                       // 1024
    int co_b = bid & 1, px_b = (bid >> 1) & 31, n = bid >> 6;
    int l0 = px_b << 7;
    int tid = threadIdx.x;
    int wv = tid >> 6, lane = tid & 63;
    int r = lane & 15, quad = lane >> 4;
    int pxl = (wv >> 1) << 6;
    int co0 = (co_b << 7) + ((wv & 1) << 6);
    const unsigned short* hrow = hb + ((size_t)n * L_ + l0) * C_;
    int q = tid & 3, pxs = tid >> 2;            // item 0: px = pxs; item 1: px = pxs+64

    uint4 pre[2];
#pragma unroll
    for (int k2 = 0; k2 < 2; ++k2)
        pre[k2] = *(const uint4*)(hrow + (size_t)(pxs + (k2 << 6)) * C_ + (q << 3));

    f32x4 acc[4][4];
#pragma unroll
    for (int i = 0; i < 4; ++i)
#pragma unroll
        for (int j = 0; j < 4; ++j) acc[i][j] = (f32x4){0.f, 0.f, 0.f, 0.f};

    for (int i = 0; i < 8; ++i) {
        int c0 = i << 5;
        unsigned short* buf = lsB[i & 1];
#pragma unroll
        for (int k2 = 0; k2 < 2; ++k2)
            *(uint4*)(buf + (pxs + (k2 << 6)) * 40 + (q << 3)) = pre[k2];
        __syncthreads();
        if (i < 7) {
#pragma unroll
            for (int k2 = 0; k2 < 2; ++k2)
                pre[k2] = *(const uint4*)(hrow + (size_t)(pxs + (k2 << 6)) * C_ + c0 + 32 + (q << 3));
        }
        short8 A[4], B[4];
#pragma unroll
        for (int t = 0; t < 4; ++t)
            A[t] = *(const short8*)(wb + (size_t)(co0 + (t << 4) + r) * C_ + c0 + (quad << 3));
#pragma unroll
        for (int t = 0; t < 4; ++t)
            B[t] = *(const short8*)(buf + (pxl + (t << 4) + r) * 40 + (quad << 3));
#pragma unroll
        for (int pxt = 0; pxt < 4; ++pxt)
#pragma unroll
            for (int cot = 0; cot < 4; ++cot)
                acc[pxt][cot] = __builtin_amdgcn_mfma_f32_16x16x32_bf16(A[cot], B[pxt], acc[pxt][cot], 0, 0, 0);
    }
#pragma unroll
    for (int pxt = 0; pxt < 4; ++pxt) {
        int px = l0 + pxl + (pxt << 4) + r;
#pragma unroll
        for (int cot = 0; cot < 4; ++cot) {
            int cb = co0 + (cot << 4) + (quad << 2);
            float4 bb = *(const float4*)(t2b + cb);
            out[((size_t)n * C_ + cb + 0) * L_ + px] = fmaxf(acc[pxt][cot][0] + bb.x, 0.f);
            out[((size_t)n * C_ + cb + 1) * L_ + px] = fmaxf(acc[pxt][cot][1] + bb.y, 0.f);
            out[((size_t)n * C_ + cb + 2) * L_ + px] = fmaxf(acc[pxt][cot][2] + bb.z, 0.f);
            out[((size_t)n * C_ + cb + 3) * L_ + px] = fmaxf(acc[pxt][cot][3] + bb.w, 0.f);
        }
    }
}

extern "C" void kernel_launch(void* const* d_in, const int* in_sizes, int n_in,
                              void* d_out, int out_size, void* d_ws, size_t ws_size,
                              hipStream_t stream)
{
    const float* feature = (const float*)d_in[0];
    const float* conv_w  = (const float*)d_in[1];
    const float* conv_b  = (const float*)d_in[2];
    const float* cent    = (const float*)d_in[3];
    const float* upfc_w  = (const float*)d_in[4];
    const float* upfc_b  = (const float*)d_in[5];
    const float* t1w     = (const float*)d_in[6];
    const float* t1b     = (const float*)d_in[7];
    const float* t2w     = (const float*)d_in[8];
    const float* t2b     = (const float*)d_in[9];

    float* ws = (float*)d_ws;                    // 43.3 MB total
    unsigned short* xnb = (unsigned short*)ws;           // 16777216 us (32 MB)
    unsigned short* hb  = xnb;                           // alias: xnb dead after k_conv
    float* rest  = ws + 8388608;
    float* rinv  = rest;                         // 65536
    float* sa    = rinv + 65536;                 // 2097152 (8 MB)
    float* up    = sa + 2097152;                 // 131072
    float* ssum  = up + 131072;                  // 512 (adjacent to up: single memset)
    float* upn   = ssum + 512;                   // 131072
    float* rowss = upn + 131072;                 // 512
    float* upvec = rowss + 512;                  // 4096
    float* t1up  = upvec + 4096;                 // 4096
    unsigned short* wbconv = (unsigned short*)upn;       // alias: upn written later by k_rowfix
    unsigned short* t1wb = (unsigned short*)sa;          // alias: sa dead after k_einsum
    unsigned short* t2wb = t1wb + 65536;
    float* out = (float*)d_out;

    hipMemsetAsync(up, 0, (131072 + 512) * sizeof(float), stream);  // up + ssum
    k_prep     <<<2048, 256, 0, stream>>>(feature, rinv, xnb);
    k_wpack    <<<288,  256, 0, stream>>>(conv_w, wbconv);
    k_conv     <<<2048, 128, 0, stream>>>(xnb, wbconv, conv_b, sa, ssum);
    k_einsum   <<<512,  256, 0, stream>>>(feature, rinv, sa, up);
    k_rowfix   <<<512,  256, 0, stream>>>(up, ssum, cent, upn, rowss);
    k_wpack2   <<<256,  256, 0, stream>>>(t1w, 512, t1wb);
    k_wpack2   <<<256,  256, 0, stream>>>(t2w, 256, t2wb);
    k_fc       <<<256,  256, 0, stream>>>(upn, rowss, upfc_w, upfc_b, upvec);
    k_t1up     <<<256,  256, 0, stream>>>(upvec, t1w, t1b, t1up);
    k_gemm1    <<<1024, 256, 0, stream>>>(feature, t1wb, t1up, hb);
    k_gemm2    <<<1024, 256, 0, stream>>>(hb, t2wb, t2b, out);
}

// Round 7
// 310.673 us; speedup vs baseline: 1.1020x; 1.0848x over previous
//
#include <hip/hip_runtime.h>
#include <cstdint>

#define N_ 16
#define C_ 256
#define H_ 64
#define W_ 64
#define L_ 4096          // H*W
#define K_ 32
#define CL_ (C_*L_)      // 1048576
#define KL_ (K_*L_)      // 131072
#define KC_ (K_*C_)      // 8192

typedef __attribute__((ext_vector_type(8))) short short8;   // 8 bf16 (4 VGPRs)
typedef __attribute__((ext_vector_type(4))) float f32x4;    // MFMA C/D frag

__device__ __forceinline__ unsigned short f2bf(float x) {   // RNE fp32->bf16
    unsigned int u = __float_as_uint(x);
    u += 0x7fffu + ((u >> 16) & 1u);
    return (unsigned short)(u >> 16);
}
__device__ __forceinline__ unsigned int pack2(float a, float b) {
    return (unsigned int)f2bf(a) | ((unsigned int)f2bf(b) << 16);
}

// async global->LDS, 16B per lane; dest = wave-uniform base + lane*16
__device__ __forceinline__ void glds16(const void* g, void* l) {
    __builtin_amdgcn_global_load_lds(
        (const __attribute__((address_space(1))) unsigned int*)g,
        (__attribute__((address_space(3))) unsigned int*)l, 16, 0, 0);
}

// ---------- K1: fused rinv + xn(bf16) transposed to (n,l,c) ----------
__global__ __launch_bounds__(256) void k_prep(
    const float* __restrict__ f, float* __restrict__ rinv,
    unsigned short* __restrict__ xnb)
{
    __shared__ float tile[256 * 34];            // [c][l], stride 34 (conflict-free)
    __shared__ float ssred[8 * 33];
    __shared__ float rbuf[32];
    int bid = blockIdx.x;
    int n = bid >> 7;
    int l0 = (bid & 127) << 5;
    int tid = threadIdx.x;
    int l = tid & 31, cb = tid >> 5;            // cb 0..7
    const float* fp = f + (size_t)n * CL_ + l0 + l;
    float ss = 0.f;
#pragma unroll
    for (int i = 0; i < 32; ++i) {
        int c = (cb << 5) + i;
        float v = fp[(size_t)c * L_];
        tile[c * 34 + l] = v;
        ss = fmaf(v, v, ss);
    }
    ssred[cb * 33 + l] = ss;
    __syncthreads();
    if (tid < 32) {
        float s = 0.f;
#pragma unroll
        for (int j = 0; j < 8; ++j) s += ssred[j * 33 + tid];
        float ri = 1.0f / fmaxf(sqrtf(s), 1e-12f);
        rinv[n * L_ + l0 + tid] = ri;
        rbuf[tid] = ri;
    }
    __syncthreads();
    float ri = rbuf[l];
    unsigned short* op = xnb + ((size_t)n * L_ + l0 + l) * C_ + (cb << 5);
#pragma unroll
    for (int g = 0; g < 4; ++g) {
        unsigned int pk[4];
#pragma unroll
        for (int d = 0; d < 4; ++d) {
            int c = (cb << 5) + (g << 3) + (d << 1);
            pk[d] = pack2(tile[c * 34 + l] * ri, tile[(c + 1) * 34 + l] * ri);
        }
        *(uint4*)(op + (g << 3)) = make_uint4(pk[0], pk[1], pk[2], pk[3]);
    }
}

// ---------- K2: repack conv weights -> wb[t][ch][q][k][8] bf16 ----------
// linear = ((t*8 + ch)*4 + q)*256 + k*8 + j, with c = ch*32+q*8+j.
// Panel (t,ch) = 2048 B contiguous -> perfect for global_load_lds (2 x 1KB).
__global__ __launch_bounds__(256) void k_wpack(const float* __restrict__ w, unsigned short* __restrict__ wb) {
    int i = blockIdx.x * 256 + threadIdx.x;     // 73728 = 9*8*4*256
    int j = i & 7;
    int k = (i >> 3) & 31;
    int q = (i >> 8) & 3;
    int ch = (i >> 10) & 7;
    int t = i >> 13;
    int c = (ch << 5) + (q << 3) + j;
    wb[i] = f2bf(w[k * 2304 + c * 9 + t]);
}

// ---------- generic 256x256 weight pack (row stride in floats) ----------
__global__ __launch_bounds__(256) void k_wpack2(const float* __restrict__ w, int stride,
                                                unsigned short* __restrict__ wb) {
    int i = blockIdx.x * 256 + threadIdx.x;     // 65536
    int co = i >> 8, ci = i & 255;
    wb[i] = f2bf(w[(size_t)co * stride + ci]);
}

// ---------- K3: MFMA 3x3 conv, FULL async-LDS staging (B and W), fused softmax+ssum ----------
// Round-7 structural fix: BOTH pixel-halo and per-chunk weight slice staged via
// global_load_lds (zero staging registers -> no spill possible; zero global
// loads in compute phase -> no vmcnt entanglement). Per chunk: issue 13
// glds16/wave for chunk i+1 right after the barrier, compute chunk i purely
// from LDS (ds_read_b128 + MFMA, lgkm domain). One vmcnt(0)+barrier per chunk,
// drain hidden under the full compute phase. OOB halo lanes redirect SOURCE to
// a zeroed pad (dest stays linear, rule #21). LDS 50 KB -> 3 blocks/CU (r5
// proved TLP-insensitivity). Cell maps verified against r4's working A/B addressing.
// B LDS: [row(3)][q(4)][px(34)] 16B cells -> B-read 2-way bank (free).
// W LDS: [t(9)][q(4)][k(32)] 16B cells -> A-read 2-way bank (free).
__global__ __launch_bounds__(128, 2) void k_conv(
    const unsigned short* __restrict__ xnb, const unsigned short* __restrict__ wb,
    const float* __restrict__ bias, const float* __restrict__ zpad,
    float* __restrict__ sa, float* __restrict__ ssum)
{
    __shared__ __align__(16) unsigned short lsB[2][408 * 8];    // 2 x 6528 B
    __shared__ __align__(16) unsigned short lsW[2][1152 * 8];   // 2 x 18432 B
    __shared__ float sred[2][32];
    int bid = blockIdx.x;                       // 2048 = px_b(2) x y(64) x n(16)
    int n = bid & 15, y = (bid >> 4) & 63, px_b = bid >> 10;   // XCD swizzle: n%8 = XCD
    int tid = threadIdx.x;
    int wv = tid >> 6, lane = tid & 63;
    int r = lane & 15, quad = lane >> 4;
    int pxw = (wv << 4) + r;                    // block-local out x (0..31)
    int xbase = (px_b << 5) - 1;                // input col of halo px 0
    const unsigned short* xb = xnb + (size_t)n * CL_;
    const unsigned short* zp = (const unsigned short*)zpad;

    // B staging: 408 cells; wave wv instr k covers cells [wv*64 + k*128, +64)
    const unsigned short* bsrc[4];
    bool bact[4];
#pragma unroll
    for (int k = 0; k < 4; ++k) {
        int c = (wv << 6) + (k << 7) + lane;
        bool act = c < 408;
        int cc = act ? c : 0;
        int row = cc / 136;
        int rem = cc - row * 136;
        int q = rem / 34;
        int px = rem - q * 34;
        int yy = y + row - 1, xx = xbase + px;
        bool ok = act && ((unsigned)yy < 64u) && ((unsigned)xx < 64u);
        bsrc[k] = ok ? (xb + (((size_t)(yy << 6) + xx) << 8) + (q << 3)) : zp;
        bact[k] = act;
    }

    f32x4 acc0 = (f32x4){0.f, 0.f, 0.f, 0.f};
    f32x4 acc1 = (f32x4){0.f, 0.f, 0.f, 0.f};

    // prologue: stage chunk 0 into buffer 0
    {
#pragma unroll
        for (int k = 0; k < 4; ++k)
            if (bact[k]) glds16(bsrc[k], lsB[0] + (((wv << 6) + (k << 7)) << 3));
#pragma unroll
        for (int k = 0; k < 9; ++k) {
            int idx = wv * 9 + k;               // 0..17
            int t = idx >> 1, h = idx & 1;
            glds16(wb + (t << 13) + (h << 9) + (lane << 3), lsW[0] + (idx << 9));
        }
    }

    for (int i = 0; i < 8; ++i) {
        asm volatile("s_waitcnt vmcnt(0)" ::: "memory");   // chunk i staged
        __syncthreads();
        if (i < 7) {                            // issue prefetch for chunk i+1 (other buffer)
            int c1 = (i + 1) << 5;              // B source advance: 32 shorts/chunk
            unsigned short* dB = lsB[(i + 1) & 1];
            unsigned short* dW = lsW[(i + 1) & 1];
#pragma unroll
            for (int k = 0; k < 4; ++k)
                if (bact[k]) glds16(bsrc[k] + c1, dB + (((wv << 6) + (k << 7)) << 3));
#pragma unroll
            for (int k = 0; k < 9; ++k) {
                int idx = wv * 9 + k;
                int t = idx >> 1, h = idx & 1;
                glds16(wb + (t << 13) + (h << 9) + ((i + 1) << 10) + (lane << 3),
                       dW + (idx << 9));
            }
        }
        // compute chunk i: pure LDS + MFMA
        const unsigned short* bufB = lsB[i & 1];
        const unsigned short* bufW = lsW[i & 1];
#pragma unroll
        for (int dy = 0; dy < 3; ++dy) {
#pragma unroll
            for (int dx = 0; dx < 3; ++dx) {
                int t = dy * 3 + dx;
                short8 B  = *(const short8*)(bufB + ((((dy << 2) + quad) * 34 + (pxw + dx)) << 3));
                short8 A0 = *(const short8*)(bufW + (((t << 7) + (quad << 5) + r) << 3));
                short8 A1 = *(const short8*)(bufW + (((t << 7) + (quad << 5) + 16 + r) << 3));
                acc0 = __builtin_amdgcn_mfma_f32_16x16x32_bf16(A0, B, acc0, 0, 0, 0);
                acc1 = __builtin_amdgcn_mfma_f32_16x16x32_bf16(A1, B, acc1, 0, 0, 0);
            }
        }
    }
    // bias + softmax over k (32 values per px: 4 quads x 8 regs)
    float4 b0 = *(const float4*)(bias + (quad << 2));
    float4 b1 = *(const float4*)(bias + 16 + (quad << 2));
    float v[8];
    v[0] = acc0[0] + b0.x; v[1] = acc0[1] + b0.y; v[2] = acc0[2] + b0.z; v[3] = acc0[3] + b0.w;
    v[4] = acc1[0] + b1.x; v[5] = acc1[1] + b1.y; v[6] = acc1[2] + b1.z; v[7] = acc1[3] + b1.w;
    float mx = v[0];
#pragma unroll
    for (int j = 1; j < 8; ++j) mx = fmaxf(mx, v[j]);
    mx = fmaxf(mx, __shfl_xor(mx, 16));
    mx = fmaxf(mx, __shfl_xor(mx, 32));
    float s = 0.f;
#pragma unroll
    for (int j = 0; j < 8; ++j) { v[j] = __expf(v[j] - mx); s += v[j]; }
    s += __shfl_xor(s, 16);
    s += __shfl_xor(s, 32);
    float rs = 1.0f / s;
    float sv8[8];
#pragma unroll
    for (int j = 0; j < 8; ++j) sv8[j] = v[j] * rs;
    int l = (y << 6) + (px_b << 5) + pxw;
    float* sp = sa + (size_t)n * KL_ + l;
#pragma unroll
    for (int j = 0; j < 4; ++j) {
        sp[(size_t)((quad << 2) + j) * L_] = sv8[j];
        sp[(size_t)(16 + (quad << 2) + j) * L_] = sv8[4 + j];
    }
    // fused ssum: reduce over this wave's 16 px (lane bits 0-3), combine 2 waves
#pragma unroll
    for (int j = 0; j < 8; ++j) {
        float a = sv8[j];
        a += __shfl_xor(a, 1); a += __shfl_xor(a, 2);
        a += __shfl_xor(a, 4); a += __shfl_xor(a, 8);
        sv8[j] = a;
    }
    if (r == 0) {
#pragma unroll
        for (int j = 0; j < 4; ++j) {
            sred[wv][(quad << 2) + j] = sv8[j];
            sred[wv][16 + (quad << 2) + j] = sv8[4 + j];
        }
    }
    __syncthreads();
    if (tid < 32) {
        float t = sred[0][tid] + sred[1][tid];
        atomicAdd(ssum + n * K_ + tid, t);
    }
}

// ---------- K5: up[n,k,c] += sum_l sa[n,k,l] * xn[n,c,l] ----------
__global__ __launch_bounds__(256) void k_einsum(
    const float* __restrict__ f, const float* __restrict__ rinv,
    const float* __restrict__ sa, float* __restrict__ up)
{
    __shared__ float xn_s[C_ * 33];
    __shared__ float sa_s[K_ * 32];
    int bid = blockIdx.x;                       // 512
    int n = bid >> 5;
    int l0 = (bid & 31) << 7;
    int tid = threadIdx.x;
    int kq = tid >> 5, cq = tid & 31;
    float acc[4][8];
#pragma unroll
    for (int i = 0; i < 4; ++i)
#pragma unroll
        for (int j = 0; j < 8; ++j) acc[i][j] = 0.f;

    for (int ch = 0; ch < 4; ++ch) {
        int lc = l0 + (ch << 5);
        __syncthreads();
        {
            int crow = tid >> 3, lq = (tid & 7) << 2;
#pragma unroll
            for (int p = 0; p < 8; ++p) {
                int c = (p << 5) + crow;
                float4 f4 = *(const float4*)(f + (size_t)n * CL_ + (size_t)c * L_ + lc + lq);
                float4 r4 = *(const float4*)(rinv + n * L_ + lc + lq);
                float* d = xn_s + c * 33 + lq;
                d[0] = f4.x * r4.x; d[1] = f4.y * r4.y; d[2] = f4.z * r4.z; d[3] = f4.w * r4.w;
            }
        }
        {
            int k = tid >> 3, lq = (tid & 7) << 2;
            float4 a4 = *(const float4*)(sa + (size_t)n * KL_ + (size_t)k * L_ + lc + lq);
            *(float4*)(sa_s + (k << 5) + lq) = a4;
        }
        __syncthreads();
#pragma unroll 4
        for (int l = 0; l < 32; ++l) {
            float sv[4], xv[8];
#pragma unroll
            for (int i = 0; i < 4; ++i) sv[i] = sa_s[((kq << 2) + i) * 32 + l];
#pragma unroll
            for (int j = 0; j < 8; ++j) xv[j] = xn_s[(cq + (j << 5)) * 33 + l];
#pragma unroll
            for (int i = 0; i < 4; ++i)
#pragma unroll
                for (int j = 0; j < 8; ++j) acc[i][j] = fmaf(sv[i], xv[j], acc[i][j]);
        }
    }
    float* upp = up + (size_t)n * KC_;
#pragma unroll
    for (int i = 0; i < 4; ++i)
#pragma unroll
        for (int j = 0; j < 8; ++j)
            atomicAdd(upp + ((kq << 2) + i) * C_ + cq + (j << 5), acc[i][j]);
}

// ---------- K6: subtract centroid term, l2norm rows, record row sumsq ----------
__global__ __launch_bounds__(256) void k_rowfix(
    const float* __restrict__ up, const float* __restrict__ ssum,
    const float* __restrict__ cent, float* __restrict__ upn, float* __restrict__ rowss)
{
    __shared__ float red[256];
    int bid = blockIdx.x;                       // n*K + k
    int k = bid & 31;
    float sv = ssum[bid];
    float v = up[(size_t)bid * C_ + threadIdx.x] - sv * cent[k * C_ + threadIdx.x];
    red[threadIdx.x] = v * v; __syncthreads();
    for (int st = 128; st > 0; st >>= 1) {
        if (threadIdx.x < st) red[threadIdx.x] += red[threadIdx.x + st];
        __syncthreads();
    }
    float ss = red[0];
    float ri = 1.0f / fmaxf(sqrtf(ss), 1e-12f);
    upn[(size_t)bid * C_ + threadIdx.x] = v * ri;
    if (threadIdx.x == 0) rowss[bid] = ss * ri * ri;
}

// ---------- K7: global l2norm + FC, one block per output channel c ----------
__global__ __launch_bounds__(256) void k_fc(
    const float* __restrict__ upn, const float* __restrict__ rowss,
    const float* __restrict__ w, const float* __restrict__ b,
    float* __restrict__ upvec)
{
    __shared__ float rnb[16];
    __shared__ float red[16][5];
    int c = blockIdx.x;                         // 256
    int tid = threadIdx.x;
    int wv = tid >> 6, lane = tid & 63;
    if (tid < 16) {
        float ts = 0.f;
#pragma unroll
        for (int k = 0; k < K_; ++k) ts += rowss[(tid << 5) + k];
        rnb[tid] = 1.0f / fmaxf(sqrtf(ts), 1e-12f);
    }
    float acc[16];
#pragma unroll
    for (int n = 0; n < 16; ++n) acc[n] = 0.f;
    const float* wr = w + (size_t)c * KC_;
#pragma unroll
    for (int g = 0; g < 8; ++g) {
        int kc = (g << 10) + (tid << 2);
        float4 w4 = *(const float4*)(wr + kc);
#pragma unroll
        for (int n = 0; n < 16; ++n) {
            float4 u4 = *(const float4*)(upn + n * KC_ + kc);
            acc[n] += w4.x * u4.x + w4.y * u4.y + w4.z * u4.z + w4.w * u4.w;
        }
    }
#pragma unroll
    for (int n = 0; n < 16; ++n) {
        float a = acc[n];
#pragma unroll
        for (int s = 1; s < 64; s <<= 1) a += __shfl_xor(a, s);
        if (lane == 0) red[n][wv] = a;
    }
    __syncthreads();
    if (tid < 16) {
        float v = red[tid][0] + red[tid][1] + red[tid][2] + red[tid][3];
        upvec[tid * C_ + c] = v * rnb[tid] + b[c];
    }
}

// ---------- K8: t1up[n,co] = t1_w[co,256:512] . upvec[n,:] + t1_b[co] ----------
__global__ __launch_bounds__(256) void k_t1up(
    const float* __restrict__ upvec, const float* __restrict__ t1w,
    const float* __restrict__ t1b, float* __restrict__ t1up)
{
    __shared__ float wld[256];
    int co = blockIdx.x;                        // 256
    int tid = threadIdx.x;
    wld[tid] = t1w[(size_t)co * 512 + 256 + tid];
    __syncthreads();
    int n = tid >> 4, s = tid & 15;
    float a = 0.f;
#pragma unroll
    for (int i = 0; i < 16; ++i)
        a += wld[s + (i << 4)] * upvec[n * C_ + s + (i << 4)];
#pragma unroll
    for (int st = 1; st < 16; st <<= 1) a += __shfl_xor(a, st);
    if (s == 0) t1up[n * C_ + co] = a + t1b[co];
}

// ---------- K9: MFMA gemm1, pipelined LDS-staged B from fp32 feature ----------
// hb[n,l,co] = bf16(relu(f[n,:,l]·t1wb[co,:] + t1up[n,co]))
__global__ __launch_bounds__(256) void k_gemm1(
    const float* __restrict__ f, const unsigned short* __restrict__ wb,
    const float* __restrict__ t1up, unsigned short* __restrict__ hb)
{
    __shared__ __align__(16) unsigned int lsB[2][128 * 20];     // px stride 20 uints (padded)
    int bid = blockIdx.x;                       // 1024 = n(16) x px_b(32) x co_b(2)
    int co_b = bid & 1, px_b = (bid >> 1) & 31, n = bid >> 6;
    int l0 = px_b << 7;
    int tid = threadIdx.x;
    int wv = tid >> 6, lane = tid & 63;
    int r = lane & 15, quad = lane >> 4;
    int pxl = (wv >> 1) << 6;                   // block-local px base for wave
    int co0 = (co_b << 7) + ((wv & 1) << 6);
    const float* fb_ = f + (size_t)n * CL_ + l0;
    int c2 = tid & 15, pxg = tid >> 4;          // item 0; item 1 = +256 -> pxg+16

    unsigned int pk[2][4];
#pragma unroll
    for (int k2 = 0; k2 < 2; ++k2) {
        const float* s0 = fb_ + (size_t)(c2 << 1) * L_ + ((pxg + (k2 << 4)) << 2);
        float4 a = *(const float4*)s0;
        float4 b = *(const float4*)(s0 + L_);
        pk[k2][0] = pack2(a.x, b.x); pk[k2][1] = pack2(a.y, b.y);
        pk[k2][2] = pack2(a.z, b.z); pk[k2][3] = pack2(a.w, b.w);
    }
    f32x4 acc[4][4];
#pragma unroll
    for (int i = 0; i < 4; ++i)
#pragma unroll
        for (int j = 0; j < 4; ++j) acc[i][j] = (f32x4){0.f, 0.f, 0.f, 0.f};

    for (int i = 0; i < 8; ++i) {
        int c0 = i << 5;
        unsigned int* buf = lsB[i & 1];
#pragma unroll
        for (int k2 = 0; k2 < 2; ++k2) {
            int base = (pxg + (k2 << 4)) * 80 + c2;     // 4 px * 20-uint stride
            buf[base]      = pk[k2][0];
            buf[base + 20] = pk[k2][1];
            buf[base + 40] = pk[k2][2];
            buf[base + 60] = pk[k2][3];
        }
        __syncthreads();
        if (i < 7) {
#pragma unroll
            for (int k2 = 0; k2 < 2; ++k2) {
                const float* s0 = fb_ + (size_t)(c0 + 32 + (c2 << 1)) * L_ + ((pxg + (k2 << 4)) << 2);
                float4 a = *(const float4*)s0;
                float4 b = *(const float4*)(s0 + L_);
                pk[k2][0] = pack2(a.x, b.x); pk[k2][1] = pack2(a.y, b.y);
                pk[k2][2] = pack2(a.z, b.z); pk[k2][3] = pack2(a.w, b.w);
            }
        }
        short8 A[4], B[4];
#pragma unroll
        for (int t = 0; t < 4; ++t)
            A[t] = *(const short8*)(wb + (size_t)(co0 + (t << 4) + r) * C_ + c0 + (quad << 3));
#pragma unroll
        for (int t = 0; t < 4; ++t)
            B[t] = *(const short8*)((const unsigned short*)buf + (pxl + (t << 4) + r) * 40 + (quad << 3));
#pragma unroll
        for (int pxt = 0; pxt < 4; ++pxt)
#pragma unroll
            for (int cot = 0; cot < 4; ++cot)
                acc[pxt][cot] = __builtin_amdgcn_mfma_f32_16x16x32_bf16(A[cot], B[pxt], acc[pxt][cot], 0, 0, 0);
    }
#pragma unroll
    for (int pxt = 0; pxt < 4; ++pxt) {
        int px = l0 + pxl + (pxt << 4) + r;
        unsigned short* orow = hb + ((size_t)n * L_ + px) * C_;
#pragma unroll
        for (int cot = 0; cot < 4; ++cot) {
            int cb = co0 + (cot << 4) + (quad << 2);
            float4 bb = *(const float4*)(t1up + n * C_ + cb);
            unsigned int p0 = pack2(fmaxf(acc[pxt][cot][0] + bb.x, 0.f),
                                    fmaxf(acc[pxt][cot][1] + bb.y, 0.f));
            unsigned int p1 = pack2(fmaxf(acc[pxt][cot][2] + bb.z, 0.f),
                                    fmaxf(acc[pxt][cot][3] + bb.w, 0.f));
            *(uint2*)(orow + cb) = make_uint2(p0, p1);
        }
    }
}

// ---------- K10: MFMA gemm2, pipelined LDS-staged B from hb ----------
// out[n,co,l] = relu(hb[n,l,:]·t2wb[co,:] + t2b[co])
__global__ __launch_bounds__(256) void k_gemm2(
    const unsigned short* __restrict__ hb, const unsigned short* __restrict__ wb,
    const float* __restrict__ t2b, float* __restrict__ out)
{
    __shared__ __align__(16) unsigned short lsB[2][128 * 40];   // px stride 40 ushorts (padded)
    int bid = blockIdx.x;                       // 1024
    int co_b = bid & 1, px_b = (bid >> 1) & 31, n = bid >> 6;
    int l0 = px_b << 7;
    int tid = threadIdx.x;
    int wv = tid >> 6, lane = tid & 63;
    int r = lane & 15, quad = lane >> 4;
    int pxl = (wv >> 1) << 6;
    int co0 = (co_b << 7) + ((wv & 1) << 6);
    const unsigned short* hrow = hb + ((size_t)n * L_ + l0) * C_;
    int q = tid & 3, pxs = tid >> 2;            // item 0: px = pxs; item 1: px = pxs+64

    uint4 pre[2];
#pragma unroll
    for (int k2 = 0; k2 < 2; ++k2)
        pre[k2] = *(const uint4*)(hrow + (size_t)(pxs + (k2 << 6)) * C_ + (q << 3));

    f32x4 acc[4][4];
#pragma unroll
    for (int i = 0; i < 4; ++i)
#pragma unroll
        for (int j = 0; j < 4; ++j) acc[i][j] = (f32x4){0.f, 0.f, 0.f, 0.f};

    for (int i = 0; i < 8; ++i) {
        int c0 = i << 5;
        unsigned short* buf = lsB[i & 1];
#pragma unroll
        for (int k2 = 0; k2 < 2; ++k2)
            *(uint4*)(buf + (pxs + (k2 << 6)) * 40 + (q << 3)) = pre[k2];
        __syncthreads();
        if (i < 7) {
#pragma unroll
            for (int k2 = 0; k2 < 2; ++k2)
                pre[k2] = *(const uint4*)(hrow + (size_t)(pxs + (k2 << 6)) * C_ + c0 + 32 + (q << 3));
        }
        short8 A[4], B[4];
#pragma unroll
        for (int t = 0; t < 4; ++t)
            A[t] = *(const short8*)(wb + (size_t)(co0 + (t << 4) + r) * C_ + c0 + (quad << 3));
#pragma unroll
        for (int t = 0; t < 4; ++t)
            B[t] = *(const short8*)(buf + (pxl + (t << 4) + r) * 40 + (quad << 3));
#pragma unroll
        for (int pxt = 0; pxt < 4; ++pxt)
#pragma unroll
            for (int cot = 0; cot < 4; ++cot)
                acc[pxt][cot] = __builtin_amdgcn_mfma_f32_16x16x32_bf16(A[cot], B[pxt], acc[pxt][cot], 0, 0, 0);
    }
#pragma unroll
    for (int pxt = 0; pxt < 4; ++pxt) {
        int px = l0 + pxl + (pxt << 4) + r;
#pragma unroll
        for (int cot = 0; cot < 4; ++cot) {
            int cb = co0 + (cot << 4) + (quad << 2);
            float4 bb = *(const float4*)(t2b + cb);
            out[((size_t)n * C_ + cb + 0) * L_ + px] = fmaxf(acc[pxt][cot][0] + bb.x, 0.f);
            out[((size_t)n * C_ + cb + 1) * L_ + px] = fmaxf(acc[pxt][cot][1] + bb.y, 0.f);
            out[((size_t)n * C_ + cb + 2) * L_ + px] = fmaxf(acc[pxt][cot][2] + bb.z, 0.f);
            out[((size_t)n * C_ + cb + 3) * L_ + px] = fmaxf(acc[pxt][cot][3] + bb.w, 0.f);
        }
    }
}

extern "C" void kernel_launch(void* const* d_in, const int* in_sizes, int n_in,
                              void* d_out, int out_size, void* d_ws, size_t ws_size,
                              hipStream_t stream)
{
    const float* feature = (const float*)d_in[0];
    const float* conv_w  = (const float*)d_in[1];
    const float* conv_b  = (const float*)d_in[2];
    const float* cent    = (const float*)d_in[3];
    const float* upfc_w  = (const float*)d_in[4];
    const float* upfc_b  = (const float*)d_in[5];
    const float* t1w     = (const float*)d_in[6];
    const float* t1b     = (const float*)d_in[7];
    const float* t2w     = (const float*)d_in[8];
    const float* t2b     = (const float*)d_in[9];

    float* ws = (float*)d_ws;                    // 43.3 MB total
    unsigned short* xnb = (unsigned short*)ws;           // 16777216 us (32 MB)
    unsigned short* hb  = xnb;                           // alias: xnb dead after k_conv
    float* rest  = ws + 8388608;
    float* rinv  = rest;                         // 65536
    float* sa    = rinv + 65536;                 // 2097152 (8 MB)
    float* up    = sa + 2097152;                 // 131072
    float* ssum  = up + 131072;                  // 512
    float* zpad  = ssum + 512;                   // 512 (zeroed: OOB redirect for glds)
    float* upn   = zpad + 512;                   // 131072
    float* rowss = upn + 131072;                 // 512
    float* upvec = rowss + 512;                  // 4096
    float* t1up  = upvec + 4096;                 // 4096
    unsigned short* wbconv = (unsigned short*)upn;       // alias: upn written later by k_rowfix
    unsigned short* t1wb = (unsigned short*)sa;          // alias: sa dead after k_einsum
    unsigned short* t2wb = t1wb + 65536;
    float* out = (float*)d_out;

    hipMemsetAsync(up, 0, (131072 + 512 + 512) * sizeof(float), stream);  // up + ssum + zpad
    k_prep     <<<2048, 256, 0, stream>>>(feature, rinv, xnb);
    k_wpack    <<<288,  256, 0, stream>>>(conv_w, wbconv);
    k_conv     <<<2048, 128, 0, stream>>>(xnb, wbconv, conv_b, zpad, sa, ssum);
    k_einsum   <<<512,  256, 0, stream>>>(feature, rinv, sa, up);
    k_rowfix   <<<512,  256, 0, stream>>>(up, ssum, cent, upn, rowss);
    k_wpack2   <<<256,  256, 0, stream>>>(t1w, 512, t1wb);
    k_wpack2   <<<256,  256, 0, stream>>>(t2w, 256, t2wb);
    k_fc       <<<256,  256, 0, stream>>>(upn, rowss, upfc_w, upfc_b, upvec);
    k_t1up     <<<256,  256, 0, stream>>>(upvec, t1w, t1b, t1up);
    k_gemm1    <<<1024, 256, 0, stream>>>(feature, t1wb, t1up, hb);
    k_gemm2    <<<1024, 256, 0, stream>>>(hb, t2wb, t2b, out);
}

// Round 8
// 299.808 us; speedup vs baseline: 1.1419x; 1.0362x over previous
//
#include <hip/hip_runtime.h>
#include <cstdint>

#define N_ 16
#define C_ 256
#define H_ 64
#define W_ 64
#define L_ 4096          // H*W
#define K_ 32
#define CL_ (C_*L_)      // 1048576
#define KL_ (K_*L_)      // 131072
#define KC_ (K_*C_)      // 8192

typedef __attribute__((ext_vector_type(8))) short short8;   // 8 bf16 (4 VGPRs)
typedef __attribute__((ext_vector_type(4))) float f32x4;    // MFMA C/D frag

__device__ __forceinline__ unsigned short f2bf(float x) {   // RNE fp32->bf16
    unsigned int u = __float_as_uint(x);
    u += 0x7fffu + ((u >> 16) & 1u);
    return (unsigned short)(u >> 16);
}
__device__ __forceinline__ unsigned int pack2(float a, float b) {
    return (unsigned int)f2bf(a) | ((unsigned int)f2bf(b) << 16);
}

// async global->LDS, 16B per lane; dest = wave-uniform base + lane*16
__device__ __forceinline__ void glds16(const void* g, void* l) {
    __builtin_amdgcn_global_load_lds(
        (const __attribute__((address_space(1))) unsigned int*)g,
        (__attribute__((address_space(3))) unsigned int*)l, 16, 0, 0);
}

// ---------- K1: fused rinv + xn(bf16) transposed to (n,l,c) ----------
__global__ __launch_bounds__(256) void k_prep(
    const float* __restrict__ f, float* __restrict__ rinv,
    unsigned short* __restrict__ xnb)
{
    __shared__ float tile[256 * 34];            // [c][l], stride 34 (conflict-free)
    __shared__ float ssred[8 * 33];
    __shared__ float rbuf[32];
    int bid = blockIdx.x;
    int n = bid >> 7;
    int l0 = (bid & 127) << 5;
    int tid = threadIdx.x;
    int l = tid & 31, cb = tid >> 5;            // cb 0..7
    const float* fp = f + (size_t)n * CL_ + l0 + l;
    float ss = 0.f;
#pragma unroll
    for (int i = 0; i < 32; ++i) {
        int c = (cb << 5) + i;
        float v = fp[(size_t)c * L_];
        tile[c * 34 + l] = v;
        ss = fmaf(v, v, ss);
    }
    ssred[cb * 33 + l] = ss;
    __syncthreads();
    if (tid < 32) {
        float s = 0.f;
#pragma unroll
        for (int j = 0; j < 8; ++j) s += ssred[j * 33 + tid];
        float ri = 1.0f / fmaxf(sqrtf(s), 1e-12f);
        rinv[n * L_ + l0 + tid] = ri;
        rbuf[tid] = ri;
    }
    __syncthreads();
    float ri = rbuf[l];
    unsigned short* op = xnb + ((size_t)n * L_ + l0 + l) * C_ + (cb << 5);
#pragma unroll
    for (int g = 0; g < 4; ++g) {
        unsigned int pk[4];
#pragma unroll
        for (int d = 0; d < 4; ++d) {
            int c = (cb << 5) + (g << 3) + (d << 1);
            pk[d] = pack2(tile[c * 34 + l] * ri, tile[(c + 1) * 34 + l] * ri);
        }
        *(uint4*)(op + (g << 3)) = make_uint4(pk[0], pk[1], pk[2], pk[3]);
    }
}

// ---------- K2: repack conv weights -> wb[t][ch][q][k][8] bf16 ----------
__global__ __launch_bounds__(256) void k_wpack(const float* __restrict__ w, unsigned short* __restrict__ wb) {
    int i = blockIdx.x * 256 + threadIdx.x;     // 73728 = 9*8*4*256
    int j = i & 7;
    int k = (i >> 3) & 31;
    int q = (i >> 8) & 3;
    int ch = (i >> 10) & 7;
    int t = i >> 13;
    int c = (ch << 5) + (q << 3) + j;
    wb[i] = f2bf(w[k * 2304 + c * 9 + t]);
}

// ---------- K2b: panelized 256x256 weight pack for glds staging ----------
// wb2[((ch*4 + q)*256 + co)*8 + j] = bf16(w[co*stride + ch*32 + q*8 + j]).
// Per-chunk W slice (ch fixed) is 4 q-panels x 256 co x 16B cells, contiguous
// in co -> 64-cell glds runs are 1KB-contiguous sources.
__global__ __launch_bounds__(256) void k_wpackp(const float* __restrict__ w, int stride,
                                                unsigned short* __restrict__ wb2) {
    int i = blockIdx.x * 256 + threadIdx.x;     // 65536
    int j = i & 7, co = (i >> 3) & 255, q = (i >> 11) & 3, ch = i >> 13;
    int ci = (ch << 5) + (q << 3) + j;
    wb2[i] = f2bf(w[(size_t)co * stride + ci]);
}

// ---------- K3: MFMA 3x3 conv, FULL async-LDS staging (r7-proven), fused softmax+ssum ----------
__global__ __launch_bounds__(128, 2) void k_conv(
    const unsigned short* __restrict__ xnb, const unsigned short* __restrict__ wb,
    const float* __restrict__ bias, const float* __restrict__ zpad,
    float* __restrict__ sa, float* __restrict__ ssum)
{
    __shared__ __align__(16) unsigned short lsB[2][408 * 8];    // 2 x 6528 B
    __shared__ __align__(16) unsigned short lsW[2][1152 * 8];   // 2 x 18432 B
    __shared__ float sred[2][32];
    int bid = blockIdx.x;                       // 2048 = px_b(2) x y(64) x n(16)
    int n = bid & 15, y = (bid >> 4) & 63, px_b = bid >> 10;   // XCD swizzle: n%8 = XCD
    int tid = threadIdx.x;
    int wv = tid >> 6, lane = tid & 63;
    int r = lane & 15, quad = lane >> 4;
    int pxw = (wv << 4) + r;                    // block-local out x (0..31)
    int xbase = (px_b << 5) - 1;                // input col of halo px 0
    const unsigned short* xb = xnb + (size_t)n * CL_;
    const unsigned short* zp = (const unsigned short*)zpad;

    // B staging: 408 cells; wave wv instr k covers cells [wv*64 + k*128, +64)
    const unsigned short* bsrc[4];
    bool bact[4];
#pragma unroll
    for (int k = 0; k < 4; ++k) {
        int c = (wv << 6) + (k << 7) + lane;
        bool act = c < 408;
        int cc = act ? c : 0;
        int row = cc / 136;
        int rem = cc - row * 136;
        int q = rem / 34;
        int px = rem - q * 34;
        int yy = y + row - 1, xx = xbase + px;
        bool ok = act && ((unsigned)yy < 64u) && ((unsigned)xx < 64u);
        bsrc[k] = ok ? (xb + (((size_t)(yy << 6) + xx) << 8) + (q << 3)) : zp;
        bact[k] = act;
    }

    f32x4 acc0 = (f32x4){0.f, 0.f, 0.f, 0.f};
    f32x4 acc1 = (f32x4){0.f, 0.f, 0.f, 0.f};

    // prologue: stage chunk 0 into buffer 0
    {
#pragma unroll
        for (int k = 0; k < 4; ++k)
            if (bact[k]) glds16(bsrc[k], lsB[0] + (((wv << 6) + (k << 7)) << 3));
#pragma unroll
        for (int k = 0; k < 9; ++k) {
            int idx = wv * 9 + k;               // 0..17
            int t = idx >> 1, h = idx & 1;
            glds16(wb + (t << 13) + (h << 9) + (lane << 3), lsW[0] + (idx << 9));
        }
    }

    for (int i = 0; i < 8; ++i) {
        asm volatile("s_waitcnt vmcnt(0)" ::: "memory");   // chunk i staged
        __syncthreads();
        if (i < 7) {                            // issue prefetch for chunk i+1 (other buffer)
            int c1 = (i + 1) << 5;              // B source advance: 32 shorts/chunk
            unsigned short* dB = lsB[(i + 1) & 1];
            unsigned short* dW = lsW[(i + 1) & 1];
#pragma unroll
            for (int k = 0; k < 4; ++k)
                if (bact[k]) glds16(bsrc[k] + c1, dB + (((wv << 6) + (k << 7)) << 3));
#pragma unroll
            for (int k = 0; k < 9; ++k) {
                int idx = wv * 9 + k;
                int t = idx >> 1, h = idx & 1;
                glds16(wb + (t << 13) + (h << 9) + ((i + 1) << 10) + (lane << 3),
                       dW + (idx << 9));
            }
        }
        // compute chunk i: pure LDS + MFMA
        const unsigned short* bufB = lsB[i & 1];
        const unsigned short* bufW = lsW[i & 1];
#pragma unroll
        for (int dy = 0; dy < 3; ++dy) {
#pragma unroll
            for (int dx = 0; dx < 3; ++dx) {
                int t = dy * 3 + dx;
                short8 B  = *(const short8*)(bufB + ((((dy << 2) + quad) * 34 + (pxw + dx)) << 3));
                short8 A0 = *(const short8*)(bufW + (((t << 7) + (quad << 5) + r) << 3));
                short8 A1 = *(const short8*)(bufW + (((t << 7) + (quad << 5) + 16 + r) << 3));
                acc0 = __builtin_amdgcn_mfma_f32_16x16x32_bf16(A0, B, acc0, 0, 0, 0);
                acc1 = __builtin_amdgcn_mfma_f32_16x16x32_bf16(A1, B, acc1, 0, 0, 0);
            }
        }
    }
    // bias + softmax over k (32 values per px: 4 quads x 8 regs)
    float4 b0 = *(const float4*)(bias + (quad << 2));
    float4 b1 = *(const float4*)(bias + 16 + (quad << 2));
    float v[8];
    v[0] = acc0[0] + b0.x; v[1] = acc0[1] + b0.y; v[2] = acc0[2] + b0.z; v[3] = acc0[3] + b0.w;
    v[4] = acc1[0] + b1.x; v[5] = acc1[1] + b1.y; v[6] = acc1[2] + b1.z; v[7] = acc1[3] + b1.w;
    float mx = v[0];
#pragma unroll
    for (int j = 1; j < 8; ++j) mx = fmaxf(mx, v[j]);
    mx = fmaxf(mx, __shfl_xor(mx, 16));
    mx = fmaxf(mx, __shfl_xor(mx, 32));
    float s = 0.f;
#pragma unroll
    for (int j = 0; j < 8; ++j) { v[j] = __expf(v[j] - mx); s += v[j]; }
    s += __shfl_xor(s, 16);
    s += __shfl_xor(s, 32);
    float rs = 1.0f / s;
    float sv8[8];
#pragma unroll
    for (int j = 0; j < 8; ++j) sv8[j] = v[j] * rs;
    int l = (y << 6) + (px_b << 5) + pxw;
    float* sp = sa + (size_t)n * KL_ + l;
#pragma unroll
    for (int j = 0; j < 4; ++j) {
        sp[(size_t)((quad << 2) + j) * L_] = sv8[j];
        sp[(size_t)(16 + (quad << 2) + j) * L_] = sv8[4 + j];
    }
    // fused ssum
#pragma unroll
    for (int j = 0; j < 8; ++j) {
        float a = sv8[j];
        a += __shfl_xor(a, 1); a += __shfl_xor(a, 2);
        a += __shfl_xor(a, 4); a += __shfl_xor(a, 8);
        sv8[j] = a;
    }
    if (r == 0) {
#pragma unroll
        for (int j = 0; j < 4; ++j) {
            sred[wv][(quad << 2) + j] = sv8[j];
            sred[wv][16 + (quad << 2) + j] = sv8[4 + j];
        }
    }
    __syncthreads();
    if (tid < 32) {
        float t = sred[0][tid] + sred[1][tid];
        atomicAdd(ssum + n * K_ + tid, t);
    }
}

// ---------- K5: up[n,k,c] += sum_l sa[n,k,l] * xn[n,c,l] ----------
__global__ __launch_bounds__(256) void k_einsum(
    const float* __restrict__ f, const float* __restrict__ rinv,
    const float* __restrict__ sa, float* __restrict__ up)
{
    __shared__ float xn_s[C_ * 33];
    __shared__ float sa_s[K_ * 32];
    int bid = blockIdx.x;                       // 512
    int n = bid >> 5;
    int l0 = (bid & 31) << 7;
    int tid = threadIdx.x;
    int kq = tid >> 5, cq = tid & 31;
    float acc[4][8];
#pragma unroll
    for (int i = 0; i < 4; ++i)
#pragma unroll
        for (int j = 0; j < 8; ++j) acc[i][j] = 0.f;

    for (int ch = 0; ch < 4; ++ch) {
        int lc = l0 + (ch << 5);
        __syncthreads();
        {
            int crow = tid >> 3, lq = (tid & 7) << 2;
#pragma unroll
            for (int p = 0; p < 8; ++p) {
                int c = (p << 5) + crow;
                float4 f4 = *(const float4*)(f + (size_t)n * CL_ + (size_t)c * L_ + lc + lq);
                float4 r4 = *(const float4*)(rinv + n * L_ + lc + lq);
                float* d = xn_s + c * 33 + lq;
                d[0] = f4.x * r4.x; d[1] = f4.y * r4.y; d[2] = f4.z * r4.z; d[3] = f4.w * r4.w;
            }
        }
        {
            int k = tid >> 3, lq = (tid & 7) << 2;
            float4 a4 = *(const float4*)(sa + (size_t)n * KL_ + (size_t)k * L_ + lc + lq);
            *(float4*)(sa_s + (k << 5) + lq) = a4;
        }
        __syncthreads();
#pragma unroll 4
        for (int l = 0; l < 32; ++l) {
            float sv[4], xv[8];
#pragma unroll
            for (int i = 0; i < 4; ++i) sv[i] = sa_s[((kq << 2) + i) * 32 + l];
#pragma unroll
            for (int j = 0; j < 8; ++j) xv[j] = xn_s[(cq + (j << 5)) * 33 + l];
#pragma unroll
            for (int i = 0; i < 4; ++i)
#pragma unroll
                for (int j = 0; j < 8; ++j) acc[i][j] = fmaf(sv[i], xv[j], acc[i][j]);
        }
    }
    float* upp = up + (size_t)n * KC_;
#pragma unroll
    for (int i = 0; i < 4; ++i)
#pragma unroll
        for (int j = 0; j < 8; ++j)
            atomicAdd(upp + ((kq << 2) + i) * C_ + cq + (j << 5), acc[i][j]);
}

// ---------- K6: subtract centroid term, l2norm rows, record row sumsq ----------
__global__ __launch_bounds__(256) void k_rowfix(
    const float* __restrict__ up, const float* __restrict__ ssum,
    const float* __restrict__ cent, float* __restrict__ upn, float* __restrict__ rowss)
{
    __shared__ float red[256];
    int bid = blockIdx.x;                       // n*K + k
    int k = bid & 31;
    float sv = ssum[bid];
    float v = up[(size_t)bid * C_ + threadIdx.x] - sv * cent[k * C_ + threadIdx.x];
    red[threadIdx.x] = v * v; __syncthreads();
    for (int st = 128; st > 0; st >>= 1) {
        if (threadIdx.x < st) red[threadIdx.x] += red[threadIdx.x + st];
        __syncthreads();
    }
    float ss = red[0];
    float ri = 1.0f / fmaxf(sqrtf(ss), 1e-12f);
    upn[(size_t)bid * C_ + threadIdx.x] = v * ri;
    if (threadIdx.x == 0) rowss[bid] = ss * ri * ri;
}

// ---------- K7: global l2norm + FC, one block per output channel c ----------
__global__ __launch_bounds__(256) void k_fc(
    const float* __restrict__ upn, const float* __restrict__ rowss,
    const float* __restrict__ w, const float* __restrict__ b,
    float* __restrict__ upvec)
{
    __shared__ float rnb[16];
    __shared__ float red[16][5];
    int c = blockIdx.x;                         // 256
    int tid = threadIdx.x;
    int wv = tid >> 6, lane = tid & 63;
    if (tid < 16) {
        float ts = 0.f;
#pragma unroll
        for (int k = 0; k < K_; ++k) ts += rowss[(tid << 5) + k];
        rnb[tid] = 1.0f / fmaxf(sqrtf(ts), 1e-12f);
    }
    float acc[16];
#pragma unroll
    for (int n = 0; n < 16; ++n) acc[n] = 0.f;
    const float* wr = w + (size_t)c * KC_;
#pragma unroll
    for (int g = 0; g < 8; ++g) {
        int kc = (g << 10) + (tid << 2);
        float4 w4 = *(const float4*)(wr + kc);
#pragma unroll
        for (int n = 0; n < 16; ++n) {
            float4 u4 = *(const float4*)(upn + n * KC_ + kc);
            acc[n] += w4.x * u4.x + w4.y * u4.y + w4.z * u4.z + w4.w * u4.w;
        }
    }
#pragma unroll
    for (int n = 0; n < 16; ++n) {
        float a = acc[n];
#pragma unroll
        for (int s = 1; s < 64; s <<= 1) a += __shfl_xor(a, s);
        if (lane == 0) red[n][wv] = a;
    }
    __syncthreads();
    if (tid < 16) {
        float v = red[tid][0] + red[tid][1] + red[tid][2] + red[tid][3];
        upvec[tid * C_ + c] = v * rnb[tid] + b[c];
    }
}

// ---------- K8: t1up[n,co] = t1_w[co,256:512] . upvec[n,:] + t1_b[co] ----------
__global__ __launch_bounds__(256) void k_t1up(
    const float* __restrict__ upvec, const float* __restrict__ t1w,
    const float* __restrict__ t1b, float* __restrict__ t1up)
{
    __shared__ float wld[256];
    int co = blockIdx.x;                        // 256
    int tid = threadIdx.x;
    wld[tid] = t1w[(size_t)co * 512 + 256 + tid];
    __syncthreads();
    int n = tid >> 4, s = tid & 15;
    float a = 0.f;
#pragma unroll
    for (int i = 0; i < 16; ++i)
        a += wld[s + (i << 4)] * upvec[n * C_ + s + (i << 4)];
#pragma unroll
    for (int st = 1; st < 16; st <<= 1) a += __shfl_xor(a, st);
    if (s == 0) t1up[n * C_ + co] = a + t1b[co];
}

// ---------- K9: MFMA gemm1 -- W via async-LDS (panel glds), B reg-staged with
// issue-early / pack-late (pack at top of NEXT chunk, load latency hidden under
// a full MFMA phase). hb[n,l,co] = bf16(relu(f[n,:,l]·t1w[co,:256] + t1up[n,co]))
__global__ __launch_bounds__(256) void k_gemm1(
    const float* __restrict__ f, const unsigned short* __restrict__ wb2,
    const float* __restrict__ t1up, unsigned short* __restrict__ hb)
{
    __shared__ __align__(16) unsigned int lsB[2][128 * 20];     // 2 x 10240 B
    __shared__ __align__(16) unsigned short lsW[2][512 * 8];    // 2 x 8192 B
    int bid = blockIdx.x;                       // 1024 = n(16) x px_b(32) x co_b(2)
    int co_b = bid & 1, px_b = (bid >> 1) & 31, n = bid >> 6;
    int l0 = px_b << 7;
    int tid = threadIdx.x;
    int wv = tid >> 6, lane = tid & 63;
    int r = lane & 15, quad = lane >> 4;
    int pxl = (wv >> 1) << 6;                   // block-local px base for wave
    int co0l = (wv & 1) << 6;                   // LDS-local co base
    int co0 = (co_b << 7) + co0l;
    const float* fb_ = f + (size_t)n * CL_ + l0;
    int c2 = tid & 15, pxg = tid >> 4;          // item 0; item 1 = +256 -> pxg+16

    float4 ra[2], rb[2];
#pragma unroll
    for (int k2 = 0; k2 < 2; ++k2) {
        const float* s0 = fb_ + (size_t)(c2 << 1) * L_ + ((pxg + (k2 << 4)) << 2);
        ra[k2] = *(const float4*)s0;
        rb[k2] = *(const float4*)(s0 + L_);
    }
#pragma unroll
    for (int k = 0; k < 2; ++k)                 // W glds chunk 0 (ch=0 panels)
        glds16(wb2 + (((wv << 8) + (co_b << 7) + (k << 6) + lane) << 3),
               lsW[0] + (((wv << 7) + (k << 6)) << 3));

    f32x4 acc[4][4];
#pragma unroll
    for (int i = 0; i < 4; ++i)
#pragma unroll
        for (int j = 0; j < 4; ++j) acc[i][j] = (f32x4){0.f, 0.f, 0.f, 0.f};

    for (int i = 0; i < 8; ++i) {
        unsigned int* buf = lsB[i & 1];
        unsigned int pk[2][4];
#pragma unroll
        for (int k2 = 0; k2 < 2; ++k2) {        // pack chunk i (regs loaded last iter)
            pk[k2][0] = pack2(ra[k2].x, rb[k2].x); pk[k2][1] = pack2(ra[k2].y, rb[k2].y);
            pk[k2][2] = pack2(ra[k2].z, rb[k2].z); pk[k2][3] = pack2(ra[k2].w, rb[k2].w);
        }
#pragma unroll
        for (int k2 = 0; k2 < 2; ++k2) {
            int base = (pxg + (k2 << 4)) * 80 + c2;     // 4 px * 20-uint stride
            buf[base]      = pk[k2][0];
            buf[base + 20] = pk[k2][1];
            buf[base + 40] = pk[k2][2];
            buf[base + 60] = pk[k2][3];
        }
        asm volatile("s_waitcnt vmcnt(0)" ::: "memory");   // W chunk i staged
        __syncthreads();
        if (i < 7) {                            // issue chunk i+1: B regs first, then W glds
#pragma unroll
            for (int k2 = 0; k2 < 2; ++k2) {
                const float* s0 = fb_ + (size_t)(((i + 1) << 5) + (c2 << 1)) * L_ + ((pxg + (k2 << 4)) << 2);
                ra[k2] = *(const float4*)s0;
                rb[k2] = *(const float4*)(s0 + L_);
            }
#pragma unroll
            for (int k = 0; k < 2; ++k)
                glds16(wb2 + ((((((i + 1) << 2) + wv) << 8) + (co_b << 7) + (k << 6) + lane) << 3),
                       lsW[(i + 1) & 1] + (((wv << 7) + (k << 6)) << 3));
        }
        const unsigned short* bufW = lsW[i & 1];
        short8 A[4], B[4];
#pragma unroll
        for (int t = 0; t < 4; ++t)
            A[t] = *(const short8*)(bufW + (((quad << 7) + co0l + (t << 4) + r) << 3));
#pragma unroll
        for (int t = 0; t < 4; ++t)
            B[t] = *(const short8*)((const unsigned short*)buf + (pxl + (t << 4) + r) * 40 + (quad << 3));
#pragma unroll
        for (int pxt = 0; pxt < 4; ++pxt)
#pragma unroll
            for (int cot = 0; cot < 4; ++cot)
                acc[pxt][cot] = __builtin_amdgcn_mfma_f32_16x16x32_bf16(A[cot], B[pxt], acc[pxt][cot], 0, 0, 0);
    }
#pragma unroll
    for (int pxt = 0; pxt < 4; ++pxt) {
        int px = l0 + pxl + (pxt << 4) + r;
        unsigned short* orow = hb + ((size_t)n * L_ + px) * C_;
#pragma unroll
        for (int cot = 0; cot < 4; ++cot) {
            int cb = co0 + (cot << 4) + (quad << 2);
            float4 bb = *(const float4*)(t1up + n * C_ + cb);
            unsigned int p0 = pack2(fmaxf(acc[pxt][cot][0] + bb.x, 0.f),
                                    fmaxf(acc[pxt][cot][1] + bb.y, 0.f));
            unsigned int p1 = pack2(fmaxf(acc[pxt][cot][2] + bb.z, 0.f),
                                    fmaxf(acc[pxt][cot][3] + bb.w, 0.f));
            *(uint2*)(orow + cb) = make_uint2(p0, p1);
        }
    }
}

// ---------- K10: MFMA gemm2 -- FULL async-LDS staging (B and W via glds),
// k_conv template. out[n,co,l] = relu(hb[n,l,:]·t2w[co,:] + t2b[co])
__global__ __launch_bounds__(256) void k_gemm2(
    const unsigned short* __restrict__ hb, const unsigned short* __restrict__ wb2,
    const float* __restrict__ t2b, float* __restrict__ out)
{
    __shared__ __align__(16) unsigned short lsB[2][512 * 8];    // 2 x 8192 B
    __shared__ __align__(16) unsigned short lsW[2][512 * 8];    // 2 x 8192 B
    int bid = blockIdx.x;                       // 1024
    int co_b = bid & 1, px_b = (bid >> 1) & 31, n = bid >> 6;
    int l0 = px_b << 7;
    int tid = threadIdx.x;
    int wv = tid >> 6, lane = tid & 63;
    int r = lane & 15, quad = lane >> 4;
    int pxl = (wv >> 1) << 6;
    int co0l = (wv & 1) << 6;
    int co0 = (co_b << 7) + co0l;
    const unsigned short* hrow = hb + ((size_t)n * L_ + l0) * C_;

    // prologue: stage chunk 0 (wave wv owns q=wv panels; 2 x 64-cell runs each)
#pragma unroll
    for (int k = 0; k < 2; ++k) {
        glds16(hrow + (size_t)((k << 6) + lane) * C_ + (wv << 3),
               lsB[0] + (((wv << 7) + (k << 6)) << 3));
        glds16(wb2 + (((wv << 8) + (co_b << 7) + (k << 6) + lane) << 3),
               lsW[0] + (((wv << 7) + (k << 6)) << 3));
    }

    f32x4 acc[4][4];
#pragma unroll
    for (int i = 0; i < 4; ++i)
#pragma unroll
        for (int j = 0; j < 4; ++j) acc[i][j] = (f32x4){0.f, 0.f, 0.f, 0.f};

    for (int i = 0; i < 8; ++i) {
        asm volatile("s_waitcnt vmcnt(0)" ::: "memory");   // chunk i staged
        __syncthreads();
        if (i < 7) {
#pragma unroll
            for (int k = 0; k < 2; ++k) {
                glds16(hrow + (size_t)((k << 6) + lane) * C_ + ((i + 1) << 5) + (wv << 3),
                       lsB[(i + 1) & 1] + (((wv << 7) + (k << 6)) << 3));
                glds16(wb2 + ((((((i + 1) << 2) + wv) << 8) + (co_b << 7) + (k << 6) + lane) << 3),
                       lsW[(i + 1) & 1] + (((wv << 7) + (k << 6)) << 3));
            }
        }
        const unsigned short* bufB = lsB[i & 1];
        const unsigned short* bufW = lsW[i & 1];
        short8 A[4], B[4];
#pragma unroll
        for (int t = 0; t < 4; ++t)
            A[t] = *(const short8*)(bufW + (((quad << 7) + co0l + (t << 4) + r) << 3));
#pragma unroll
        for (int t = 0; t < 4; ++t)
            B[t] = *(const short8*)(bufB + (((quad << 7) + pxl + (t << 4) + r) << 3));
#pragma unroll
        for (int pxt = 0; pxt < 4; ++pxt)
#pragma unroll
            for (int cot = 0; cot < 4; ++cot)
                acc[pxt][cot] = __builtin_amdgcn_mfma_f32_16x16x32_bf16(A[cot], B[pxt], acc[pxt][cot], 0, 0, 0);
    }
#pragma unroll
    for (int pxt = 0; pxt < 4; ++pxt) {
        int px = l0 + pxl + (pxt << 4) + r;
#pragma unroll
        for (int cot = 0; cot < 4; ++cot) {
            int cb = co0 + (cot << 4) + (quad << 2);
            float4 bb = *(const float4*)(t2b + cb);
            out[((size_t)n * C_ + cb + 0) * L_ + px] = fmaxf(acc[pxt][cot][0] + bb.x, 0.f);
            out[((size_t)n * C_ + cb + 1) * L_ + px] = fmaxf(acc[pxt][cot][1] + bb.y, 0.f);
            out[((size_t)n * C_ + cb + 2) * L_ + px] = fmaxf(acc[pxt][cot][2] + bb.z, 0.f);
            out[((size_t)n * C_ + cb + 3) * L_ + px] = fmaxf(acc[pxt][cot][3] + bb.w, 0.f);
        }
    }
}

extern "C" void kernel_launch(void* const* d_in, const int* in_sizes, int n_in,
                              void* d_out, int out_size, void* d_ws, size_t ws_size,
                              hipStream_t stream)
{
    const float* feature = (const float*)d_in[0];
    const float* conv_w  = (const float*)d_in[1];
    const float* conv_b  = (const float*)d_in[2];
    const float* cent    = (const float*)d_in[3];
    const float* upfc_w  = (const float*)d_in[4];
    const float* upfc_b  = (const float*)d_in[5];
    const float* t1w     = (const float*)d_in[6];
    const float* t1b     = (const float*)d_in[7];
    const float* t2w     = (const float*)d_in[8];
    const float* t2b     = (const float*)d_in[9];

    float* ws = (float*)d_ws;                    // 43.3 MB total
    unsigned short* xnb = (unsigned short*)ws;           // 16777216 us (32 MB)
    unsigned short* hb  = xnb;                           // alias: xnb dead after k_conv
    float* rest  = ws + 8388608;
    float* rinv  = rest;                         // 65536
    float* sa    = rinv + 65536;                 // 2097152 (8 MB)
    float* up    = sa + 2097152;                 // 131072
    float* ssum  = up + 131072;                  // 512
    float* zpad  = ssum + 512;                   // 512 (zeroed: OOB redirect for glds)
    float* upn   = zpad + 512;                   // 131072
    float* rowss = upn + 131072;                 // 512
    float* upvec = rowss + 512;                  // 4096
    float* t1up  = upvec + 4096;                 // 4096
    unsigned short* wbconv = (unsigned short*)upn;       // alias: upn written later by k_rowfix
    unsigned short* t1wb = (unsigned short*)sa;          // alias: sa dead after k_einsum
    unsigned short* t2wb = t1wb + 65536;
    float* out = (float*)d_out;

    hipMemsetAsync(up, 0, (131072 + 512 + 512) * sizeof(float), stream);  // up + ssum + zpad
    k_prep     <<<2048, 256, 0, stream>>>(feature, rinv, xnb);
    k_wpack    <<<288,  256, 0, stream>>>(conv_w, wbconv);
    k_conv     <<<2048, 128, 0, stream>>>(xnb, wbconv, conv_b, zpad, sa, ssum);
    k_einsum   <<<512,  256, 0, stream>>>(feature, rinv, sa, up);
    k_rowfix   <<<512,  256, 0, stream>>>(up, ssum, cent, upn, rowss);
    k_wpackp   <<<256,  256, 0, stream>>>(t1w, 512, t1wb);
    k_wpackp   <<<256,  256, 0, stream>>>(t2w, 256, t2wb);
    k_fc       <<<256,  256, 0, stream>>>(upn, rowss, upfc_w, upfc_b, upvec);
    k_t1up     <<<256,  256, 0, stream>>>(upvec, t1w, t1b, t1up);
    k_gemm1    <<<1024, 256, 0, stream>>>(feature, t1wb, t1up, hb);
    k_gemm2    <<<1024, 256, 0, stream>>>(hb, t2wb, t2b, out);
}

// Round 9
// 285.837 us; speedup vs baseline: 1.1977x; 1.0489x over previous
//
#include <hip/hip_runtime.h>
#include <cstdint>

#define N_ 16
#define C_ 256
#define H_ 64
#define W_ 64
#define L_ 4096          // H*W
#define K_ 32
#define CL_ (C_*L_)      // 1048576
#define KL_ (K_*L_)      // 131072
#define KC_ (K_*C_)      // 8192

typedef __attribute__((ext_vector_type(8))) short short8;   // 8 bf16 (4 VGPRs)
typedef __attribute__((ext_vector_type(4))) float f32x4;    // MFMA C/D frag

__device__ __forceinline__ unsigned short f2bf(float x) {   // RNE fp32->bf16
    unsigned int u = __float_as_uint(x);
    u += 0x7fffu + ((u >> 16) & 1u);
    return (unsigned short)(u >> 16);
}
__device__ __forceinline__ unsigned int pack2(float a, float b) {
    return (unsigned int)f2bf(a) | ((unsigned int)f2bf(b) << 16);
}

// async global->LDS, 16B per lane; dest = wave-uniform base + lane*16
__device__ __forceinline__ void glds16(const void* g, void* l) {
    __builtin_amdgcn_global_load_lds(
        (const __attribute__((address_space(1))) unsigned int*)g,
        (__attribute__((address_space(3))) unsigned int*)l, 16, 0, 0);
}

// ---------- K1: fused rinv + snorm + xn(bf16) transposed to (n,l,c) ----------
__global__ __launch_bounds__(256) void k_prep(
    const float* __restrict__ f, float* __restrict__ rinv,
    float* __restrict__ snorm, unsigned short* __restrict__ xnb)
{
    __shared__ float tile[256 * 34];            // [c][l], stride 34 (conflict-free)
    __shared__ float ssred[8 * 33];
    __shared__ float rbuf[32];
    int bid = blockIdx.x;
    int n = bid >> 7;
    int l0 = (bid & 127) << 5;
    int tid = threadIdx.x;
    int l = tid & 31, cb = tid >> 5;            // cb 0..7
    const float* fp = f + (size_t)n * CL_ + l0 + l;
    float ss = 0.f;
#pragma unroll
    for (int i = 0; i < 32; ++i) {
        int c = (cb << 5) + i;
        float v = fp[(size_t)c * L_];
        tile[c * 34 + l] = v;
        ss = fmaf(v, v, ss);
    }
    ssred[cb * 33 + l] = ss;
    __syncthreads();
    if (tid < 32) {
        float s = 0.f;
#pragma unroll
        for (int j = 0; j < 8; ++j) s += ssred[j * 33 + tid];
        float sq = fmaxf(sqrtf(s), 1e-12f);
        float ri = 1.0f / sq;
        rinv[n * L_ + l0 + tid] = ri;
        snorm[n * L_ + l0 + tid] = sq;          // f = xn * snorm exactly (incl. clamp case)
        rbuf[tid] = ri;
    }
    __syncthreads();
    float ri = rbuf[l];
    unsigned short* op = xnb + ((size_t)n * L_ + l0 + l) * C_ + (cb << 5);
#pragma unroll
    for (int g = 0; g < 4; ++g) {
        unsigned int pk[4];
#pragma unroll
        for (int d = 0; d < 4; ++d) {
            int c = (cb << 5) + (g << 3) + (d << 1);
            pk[d] = pack2(tile[c * 34 + l] * ri, tile[(c + 1) * 34 + l] * ri);
        }
        *(uint4*)(op + (g << 3)) = make_uint4(pk[0], pk[1], pk[2], pk[3]);
    }
}

// ---------- K2: repack conv weights -> wb[t][ch][q][k][8] bf16 ----------
__global__ __launch_bounds__(256) void k_wpack(const float* __restrict__ w, unsigned short* __restrict__ wb) {
    int i = blockIdx.x * 256 + threadIdx.x;     // 73728 = 9*8*4*256
    int j = i & 7;
    int k = (i >> 3) & 31;
    int q = (i >> 8) & 3;
    int ch = (i >> 10) & 7;
    int t = i >> 13;
    int c = (ch << 5) + (q << 3) + j;
    wb[i] = f2bf(w[k * 2304 + c * 9 + t]);
}

// ---------- K2b: panelized 256x256 weight pack for glds staging ----------
// wb2[((ch*4 + q)*256 + co)*8 + j] = bf16(w[co*stride + ch*32 + q*8 + j]).
__global__ __launch_bounds__(256) void k_wpackp(const float* __restrict__ w, int stride,
                                                unsigned short* __restrict__ wb2) {
    int i = blockIdx.x * 256 + threadIdx.x;     // 65536
    int j = i & 7, co = (i >> 3) & 255, q = (i >> 11) & 3, ch = i >> 13;
    int ci = (ch << 5) + (q << 3) + j;
    wb2[i] = f2bf(w[(size_t)co * stride + ci]);
}

// ---------- K3: MFMA 3x3 conv, FULL async-LDS staging (r7-proven), fused softmax+ssum ----------
__global__ __launch_bounds__(128, 2) void k_conv(
    const unsigned short* __restrict__ xnb, const unsigned short* __restrict__ wb,
    const float* __restrict__ bias, const float* __restrict__ zpad,
    float* __restrict__ sa, float* __restrict__ ssum)
{
    __shared__ __align__(16) unsigned short lsB[2][408 * 8];    // 2 x 6528 B
    __shared__ __align__(16) unsigned short lsW[2][1152 * 8];   // 2 x 18432 B
    __shared__ float sred[2][32];
    int bid = blockIdx.x;                       // 2048 = px_b(2) x y(64) x n(16)
    int n = bid & 15, y = (bid >> 4) & 63, px_b = bid >> 10;   // XCD swizzle: n%8 = XCD
    int tid = threadIdx.x;
    int wv = tid >> 6, lane = tid & 63;
    int r = lane & 15, quad = lane >> 4;
    int pxw = (wv << 4) + r;                    // block-local out x (0..31)
    int xbase = (px_b << 5) - 1;                // input col of halo px 0
    const unsigned short* xb = xnb + (size_t)n * CL_;
    const unsigned short* zp = (const unsigned short*)zpad;

    // B staging: 408 cells; wave wv instr k covers cells [wv*64 + k*128, +64)
    const unsigned short* bsrc[4];
    bool bact[4];
#pragma unroll
    for (int k = 0; k < 4; ++k) {
        int c = (wv << 6) + (k << 7) + lane;
        bool act = c < 408;
        int cc = act ? c : 0;
        int row = cc / 136;
        int rem = cc - row * 136;
        int q = rem / 34;
        int px = rem - q * 34;
        int yy = y + row - 1, xx = xbase + px;
        bool ok = act && ((unsigned)yy < 64u) && ((unsigned)xx < 64u);
        bsrc[k] = ok ? (xb + (((size_t)(yy << 6) + xx) << 8) + (q << 3)) : zp;
        bact[k] = act;
    }

    f32x4 acc0 = (f32x4){0.f, 0.f, 0.f, 0.f};
    f32x4 acc1 = (f32x4){0.f, 0.f, 0.f, 0.f};

    // prologue: stage chunk 0 into buffer 0
    {
#pragma unroll
        for (int k = 0; k < 4; ++k)
            if (bact[k]) glds16(bsrc[k], lsB[0] + (((wv << 6) + (k << 7)) << 3));
#pragma unroll
        for (int k = 0; k < 9; ++k) {
            int idx = wv * 9 + k;               // 0..17
            int t = idx >> 1, h = idx & 1;
            glds16(wb + (t << 13) + (h << 9) + (lane << 3), lsW[0] + (idx << 9));
        }
    }

    for (int i = 0; i < 8; ++i) {
        asm volatile("s_waitcnt vmcnt(0)" ::: "memory");   // chunk i staged
        __syncthreads();
        if (i < 7) {                            // issue prefetch for chunk i+1 (other buffer)
            int c1 = (i + 1) << 5;              // B source advance: 32 shorts/chunk
            unsigned short* dB = lsB[(i + 1) & 1];
            unsigned short* dW = lsW[(i + 1) & 1];
#pragma unroll
            for (int k = 0; k < 4; ++k)
                if (bact[k]) glds16(bsrc[k] + c1, dB + (((wv << 6) + (k << 7)) << 3));
#pragma unroll
            for (int k = 0; k < 9; ++k) {
                int idx = wv * 9 + k;
                int t = idx >> 1, h = idx & 1;
                glds16(wb + (t << 13) + (h << 9) + ((i + 1) << 10) + (lane << 3),
                       dW + (idx << 9));
            }
        }
        // compute chunk i: pure LDS + MFMA
        const unsigned short* bufB = lsB[i & 1];
        const unsigned short* bufW = lsW[i & 1];
#pragma unroll
        for (int dy = 0; dy < 3; ++dy) {
#pragma unroll
            for (int dx = 0; dx < 3; ++dx) {
                int t = dy * 3 + dx;
                short8 B  = *(const short8*)(bufB + ((((dy << 2) + quad) * 34 + (pxw + dx)) << 3));
                short8 A0 = *(const short8*)(bufW + (((t << 7) + (quad << 5) + r) << 3));
                short8 A1 = *(const short8*)(bufW + (((t << 7) + (quad << 5) + 16 + r) << 3));
                acc0 = __builtin_amdgcn_mfma_f32_16x16x32_bf16(A0, B, acc0, 0, 0, 0);
                acc1 = __builtin_amdgcn_mfma_f32_16x16x32_bf16(A1, B, acc1, 0, 0, 0);
            }
        }
    }
    // bias + softmax over k (32 values per px: 4 quads x 8 regs)
    float4 b0 = *(const float4*)(bias + (quad << 2));
    float4 b1 = *(const float4*)(bias + 16 + (quad << 2));
    float v[8];
    v[0] = acc0[0] + b0.x; v[1] = acc0[1] + b0.y; v[2] = acc0[2] + b0.z; v[3] = acc0[3] + b0.w;
    v[4] = acc1[0] + b1.x; v[5] = acc1[1] + b1.y; v[6] = acc1[2] + b1.z; v[7] = acc1[3] + b1.w;
    float mx = v[0];
#pragma unroll
    for (int j = 1; j < 8; ++j) mx = fmaxf(mx, v[j]);
    mx = fmaxf(mx, __shfl_xor(mx, 16));
    mx = fmaxf(mx, __shfl_xor(mx, 32));
    float s = 0.f;
#pragma unroll
    for (int j = 0; j < 8; ++j) { v[j] = __expf(v[j] - mx); s += v[j]; }
    s += __shfl_xor(s, 16);
    s += __shfl_xor(s, 32);
    float rs = 1.0f / s;
    float sv8[8];
#pragma unroll
    for (int j = 0; j < 8; ++j) sv8[j] = v[j] * rs;
    int l = (y << 6) + (px_b << 5) + pxw;
    float* sp = sa + (size_t)n * KL_ + l;
#pragma unroll
    for (int j = 0; j < 4; ++j) {
        sp[(size_t)((quad << 2) + j) * L_] = sv8[j];
        sp[(size_t)(16 + (quad << 2) + j) * L_] = sv8[4 + j];
    }
    // fused ssum
#pragma unroll
    for (int j = 0; j < 8; ++j) {
        float a = sv8[j];
        a += __shfl_xor(a, 1); a += __shfl_xor(a, 2);
        a += __shfl_xor(a, 4); a += __shfl_xor(a, 8);
        sv8[j] = a;
    }
    if (r == 0) {
#pragma unroll
        for (int j = 0; j < 4; ++j) {
            sred[wv][(quad << 2) + j] = sv8[j];
            sred[wv][16 + (quad << 2) + j] = sv8[4 + j];
        }
    }
    __syncthreads();
    if (tid < 32) {
        float t = sred[0][tid] + sred[1][tid];
        atomicAdd(ssum + n * K_ + tid, t);
    }
}

// ---------- K5: up[n,k,c] += sum_l sa[n,k,l] * xn[n,c,l] ----------
__global__ __launch_bounds__(256) void k_einsum(
    const float* __restrict__ f, const float* __restrict__ rinv,
    const float* __restrict__ sa, float* __restrict__ up)
{
    __shared__ float xn_s[C_ * 33];
    __shared__ float sa_s[K_ * 32];
    int bid = blockIdx.x;                       // 512
    int n = bid >> 5;
    int l0 = (bid & 31) << 7;
    int tid = threadIdx.x;
    int kq = tid >> 5, cq = tid & 31;
    float acc[4][8];
#pragma unroll
    for (int i = 0; i < 4; ++i)
#pragma unroll
        for (int j = 0; j < 8; ++j) acc[i][j] = 0.f;

    for (int ch = 0; ch < 4; ++ch) {
        int lc = l0 + (ch << 5);
        __syncthreads();
        {
            int crow = tid >> 3, lq = (tid & 7) << 2;
#pragma unroll
            for (int p = 0; p < 8; ++p) {
                int c = (p << 5) + crow;
                float4 f4 = *(const float4*)(f + (size_t)n * CL_ + (size_t)c * L_ + lc + lq);
                float4 r4 = *(const float4*)(rinv + n * L_ + lc + lq);
                float* d = xn_s + c * 33 + lq;
                d[0] = f4.x * r4.x; d[1] = f4.y * r4.y; d[2] = f4.z * r4.z; d[3] = f4.w * r4.w;
            }
        }
        {
            int k = tid >> 3, lq = (tid & 7) << 2;
            float4 a4 = *(const float4*)(sa + (size_t)n * KL_ + (size_t)k * L_ + lc + lq);
            *(float4*)(sa_s + (k << 5) + lq) = a4;
        }
        __syncthreads();
#pragma unroll 4
        for (int l = 0; l < 32; ++l) {
            float sv[4], xv[8];
#pragma unroll
            for (int i = 0; i < 4; ++i) sv[i] = sa_s[((kq << 2) + i) * 32 + l];
#pragma unroll
            for (int j = 0; j < 8; ++j) xv[j] = xn_s[(cq + (j << 5)) * 33 + l];
#pragma unroll
            for (int i = 0; i < 4; ++i)
#pragma unroll
                for (int j = 0; j < 8; ++j) acc[i][j] = fmaf(sv[i], xv[j], acc[i][j]);
        }
    }
    float* upp = up + (size_t)n * KC_;
#pragma unroll
    for (int i = 0; i < 4; ++i)
#pragma unroll
        for (int j = 0; j < 8; ++j)
            atomicAdd(upp + ((kq << 2) + i) * C_ + cq + (j << 5), acc[i][j]);
}

// ---------- K6: subtract centroid term, l2norm rows, record row sumsq ----------
__global__ __launch_bounds__(256) void k_rowfix(
    const float* __restrict__ up, const float* __restrict__ ssum,
    const float* __restrict__ cent, float* __restrict__ upn, float* __restrict__ rowss)
{
    __shared__ float red[256];
    int bid = blockIdx.x;                       // n*K + k
    int k = bid & 31;
    float sv = ssum[bid];
    float v = up[(size_t)bid * C_ + threadIdx.x] - sv * cent[k * C_ + threadIdx.x];
    red[threadIdx.x] = v * v; __syncthreads();
    for (int st = 128; st > 0; st >>= 1) {
        if (threadIdx.x < st) red[threadIdx.x] += red[threadIdx.x + st];
        __syncthreads();
    }
    float ss = red[0];
    float ri = 1.0f / fmaxf(sqrtf(ss), 1e-12f);
    upn[(size_t)bid * C_ + threadIdx.x] = v * ri;
    if (threadIdx.x == 0) rowss[bid] = ss * ri * ri;
}

// ---------- K7: global l2norm + FC, one block per output channel c ----------
__global__ __launch_bounds__(256) void k_fc(
    const float* __restrict__ upn, const float* __restrict__ rowss,
    const float* __restrict__ w, const float* __restrict__ b,
    float* __restrict__ upvec)
{
    __shared__ float rnb[16];
    __shared__ float red[16][5];
    int c = blockIdx.x;                         // 256
    int tid = threadIdx.x;
    int wv = tid >> 6, lane = tid & 63;
    if (tid < 16) {
        float ts = 0.f;
#pragma unroll
        for (int k = 0; k < K_; ++k) ts += rowss[(tid << 5) + k];
        rnb[tid] = 1.0f / fmaxf(sqrtf(ts), 1e-12f);
    }
    float acc[16];
#pragma unroll
    for (int n = 0; n < 16; ++n) acc[n] = 0.f;
    const float* wr = w + (size_t)c * KC_;
#pragma unroll
    for (int g = 0; g < 8; ++g) {
        int kc = (g << 10) + (tid << 2);
        float4 w4 = *(const float4*)(wr + kc);
#pragma unroll
        for (int n = 0; n < 16; ++n) {
            float4 u4 = *(const float4*)(upn + n * KC_ + kc);
            acc[n] += w4.x * u4.x + w4.y * u4.y + w4.z * u4.z + w4.w * u4.w;
        }
    }
#pragma unroll
    for (int n = 0; n < 16; ++n) {
        float a = acc[n];
#pragma unroll
        for (int s = 1; s < 64; s <<= 1) a += __shfl_xor(a, s);
        if (lane == 0) red[n][wv] = a;
    }
    __syncthreads();
    if (tid < 16) {
        float v = red[tid][0] + red[tid][1] + red[tid][2] + red[tid][3];
        upvec[tid * C_ + c] = v * rnb[tid] + b[c];
    }
}

// ---------- K8: t1up[n,co] = t1_w[co,256:512] . upvec[n,:] + t1_b[co] ----------
__global__ __launch_bounds__(256) void k_t1up(
    const float* __restrict__ upvec, const float* __restrict__ t1w,
    const float* __restrict__ t1b, float* __restrict__ t1up)
{
    __shared__ float wld[256];
    int co = blockIdx.x;                        // 256
    int tid = threadIdx.x;
    wld[tid] = t1w[(size_t)co * 512 + 256 + tid];
    __syncthreads();
    int n = tid >> 4, s = tid & 15;
    float a = 0.f;
#pragma unroll
    for (int i = 0; i < 16; ++i)
        a += wld[s + (i << 4)] * upvec[n * C_ + s + (i << 4)];
#pragma unroll
    for (int st = 1; st < 16; st <<= 1) a += __shfl_xor(a, st);
    if (s == 0) t1up[n * C_ + co] = a + t1b[co];
}

// ---------- K9: MFMA gemm1 -- FULL async-LDS staging from xnb (bf16), merged-co.
// f[c,l] = xn[c,l]*snorm[l] exactly -> hb = bf16(relu(snorm_l*(xn·t1w[:256]) + t1up)).
// grid 512 = n(16) x px_b(32); 512 threads = 8 waves (2 px-halves x 4 co-quarters).
// Block owns px rows l0..l0+127 EXCLUSIVELY -> in-place hb-over-xnb write is safe
// (all xnb reads drain at last chunk's vmcnt(0)+barrier, before any epilogue).
__global__ __launch_bounds__(512, 2) void k_gemm1(
    const unsigned short* __restrict__ xnb, const unsigned short* __restrict__ wb2,
    const float* __restrict__ t1up, const float* __restrict__ snorm,
    unsigned short* __restrict__ hb)
{
    __shared__ __align__(16) unsigned short lsB[2][512 * 8];    // 2 x 8 KB: [q(4)][px(128)]
    __shared__ __align__(16) unsigned short lsW[2][1024 * 8];   // 2 x 16 KB: [q(4)][co(256)]
    int bid = blockIdx.x;                       // 512 = px_b(32) x n(16)
    int n = bid & 15, px_b = bid >> 4;          // XCD swizzle: n%8 = XCD
    int l0 = px_b << 7;
    int tid = threadIdx.x;
    int wv = tid >> 6, lane = tid & 63;
    int r = lane & 15, quad = lane >> 4;
    int pxl = (wv >> 2) << 6;                   // 0 or 64
    int co0 = (wv & 3) << 6;                    // 0,64,128,192
    const unsigned short* xrow = xnb + ((size_t)n * L_ + l0) * C_;

    // B cell for this lane: cb = wv*64+lane in [0,512): q=cb>>7, px=cb&127
    int cbi = (wv << 6) + lane;
    int bq = cbi >> 7, bpx = cbi & 127;
    const unsigned short* bsrc = xrow + (size_t)bpx * C_ + (bq << 3);

    // prologue: stage chunk 0
    glds16(bsrc, lsB[0] + (cbi << 3));
#pragma unroll
    for (int k = 0; k < 2; ++k) {
        int cw = (wv << 7) + (k << 6) + lane;   // [0,1024)
        glds16(wb2 + ((size_t)cw << 3), lsW[0] + (cw << 3));
    }

    f32x4 acc[4][4];
#pragma unroll
    for (int i = 0; i < 4; ++i)
#pragma unroll
        for (int j = 0; j < 4; ++j) acc[i][j] = (f32x4){0.f, 0.f, 0.f, 0.f};

    for (int i = 0; i < 8; ++i) {
        asm volatile("s_waitcnt vmcnt(0)" ::: "memory");   // chunk i staged
        __syncthreads();
        if (i < 7) {
            glds16(bsrc + ((i + 1) << 5), lsB[(i + 1) & 1] + (cbi << 3));
#pragma unroll
            for (int k = 0; k < 2; ++k) {
                int cw = (wv << 7) + (k << 6) + lane;
                glds16(wb2 + ((size_t)(((i + 1) << 10) + cw) << 3),
                       lsW[(i + 1) & 1] + (cw << 3));
            }
        }
        const unsigned short* bufB = lsB[i & 1];
        const unsigned short* bufW = lsW[i & 1];
        short8 A[4], B[4];
#pragma unroll
        for (int t = 0; t < 4; ++t)
            A[t] = *(const short8*)(bufW + (((quad << 8) + co0 + (t << 4) + r) << 3));
#pragma unroll
        for (int t = 0; t < 4; ++t)
            B[t] = *(const short8*)(bufB + (((quad << 7) + pxl + (t << 4) + r) << 3));
#pragma unroll
        for (int pxt = 0; pxt < 4; ++pxt)
#pragma unroll
            for (int cot = 0; cot < 4; ++cot)
                acc[pxt][cot] = __builtin_amdgcn_mfma_f32_16x16x32_bf16(A[cot], B[pxt], acc[pxt][cot], 0, 0, 0);
    }
#pragma unroll
    for (int pxt = 0; pxt < 4; ++pxt) {
        int px = l0 + pxl + (pxt << 4) + r;
        float sc = snorm[n * L_ + px];
        unsigned short* orow = hb + ((size_t)n * L_ + px) * C_;
#pragma unroll
        for (int cot = 0; cot < 4; ++cot) {
            int cb = co0 + (cot << 4) + (quad << 2);
            float4 bb = *(const float4*)(t1up + n * C_ + cb);
            unsigned int p0 = pack2(fmaxf(fmaf(acc[pxt][cot][0], sc, bb.x), 0.f),
                                    fmaxf(fmaf(acc[pxt][cot][1], sc, bb.y), 0.f));
            unsigned int p1 = pack2(fmaxf(fmaf(acc[pxt][cot][2], sc, bb.z), 0.f),
                                    fmaxf(fmaf(acc[pxt][cot][3], sc, bb.w), 0.f));
            *(uint2*)(orow + cb) = make_uint2(p0, p1);
        }
    }
}

// ---------- K10: MFMA gemm2 -- FULL async-LDS staging (B and W via glds) ----------
__global__ __launch_bounds__(256) void k_gemm2(
    const unsigned short* __restrict__ hb, const unsigned short* __restrict__ wb2,
    const float* __restrict__ t2b, float* __restrict__ out)
{
    __shared__ __align__(16) unsigned short lsB[2][512 * 8];    // 2 x 8192 B
    __shared__ __align__(16) unsigned short lsW[2][512 * 8];    // 2 x 8192 B
    int bid = blockIdx.x;                       // 1024
    int co_b = bid & 1, px_b = (bid >> 1) & 31, n = bid >> 6;
    int l0 = px_b << 7;
    int tid = threadIdx.x;
    int wv = tid >> 6, lane = tid & 63;
    int r = lane & 15, quad = lane >> 4;
    int pxl = (wv >> 1) << 6;
    int co0l = (wv & 1) << 6;
    int co0 = (co_b << 7) + co0l;
    const unsigned short* hrow = hb + ((size_t)n * L_ + l0) * C_;

    // prologue: stage chunk 0 (wave wv owns q=wv panels; 2 x 64-cell runs each)
#pragma unroll
    for (int k = 0; k < 2; ++k) {
        glds16(hrow + (size_t)((k << 6) + lane) * C_ + (wv << 3),
               lsB[0] + (((wv << 7) + (k << 6)) << 3));
        glds16(wb2 + (((wv << 8) + (co_b << 7) + (k << 6) + lane) << 3),
               lsW[0] + (((wv << 7) + (k << 6)) << 3));
    }

    f32x4 acc[4][4];
#pragma unroll
    for (int i = 0; i < 4; ++i)
#pragma unroll
        for (int j = 0; j < 4; ++j) acc[i][j] = (f32x4){0.f, 0.f, 0.f, 0.f};

    for (int i = 0; i < 8; ++i) {
        asm volatile("s_waitcnt vmcnt(0)" ::: "memory");   // chunk i staged
        __syncthreads();
        if (i < 7) {
#pragma unroll
            for (int k = 0; k < 2; ++k) {
                glds16(hrow + (size_t)((k << 6) + lane) * C_ + ((i + 1) << 5) + (wv << 3),
                       lsB[(i + 1) & 1] + (((wv << 7) + (k << 6)) << 3));
                glds16(wb2 + ((((((i + 1) << 2) + wv) << 8) + (co_b << 7) + (k << 6) + lane) << 3),
                       lsW[(i + 1) & 1] + (((wv << 7) + (k << 6)) << 3));
            }
        }
        const unsigned short* bufB = lsB[i & 1];
        const unsigned short* bufW = lsW[i & 1];
        short8 A[4], B[4];
#pragma unroll
        for (int t = 0; t < 4; ++t)
            A[t] = *(const short8*)(bufW + (((quad << 7) + co0l + (t << 4) + r) << 3));
#pragma unroll
        for (int t = 0; t < 4; ++t)
            B[t] = *(const short8*)(bufB + (((quad << 7) + pxl + (t << 4) + r) << 3));
#pragma unroll
        for (int pxt = 0; pxt < 4; ++pxt)
#pragma unroll
            for (int cot = 0; cot < 4; ++cot)
                acc[pxt][cot] = __builtin_amdgcn_mfma_f32_16x16x32_bf16(A[cot], B[pxt], acc[pxt][cot], 0, 0, 0);
    }
#pragma unroll
    for (int pxt = 0; pxt < 4; ++pxt) {
        int px = l0 + pxl + (pxt << 4) + r;
#pragma unroll
        for (int cot = 0; cot < 4; ++cot) {
            int cb = co0 + (cot << 4) + (quad << 2);
            float4 bb = *(const float4*)(t2b + cb);
            out[((size_t)n * C_ + cb + 0) * L_ + px] = fmaxf(acc[pxt][cot][0] + bb.x, 0.f);
            out[((size_t)n * C_ + cb + 1) * L_ + px] = fmaxf(acc[pxt][cot][1] + bb.y, 0.f);
            out[((size_t)n * C_ + cb + 2) * L_ + px] = fmaxf(acc[pxt][cot][2] + bb.z, 0.f);
            out[((size_t)n * C_ + cb + 3) * L_ + px] = fmaxf(acc[pxt][cot][3] + bb.w, 0.f);
        }
    }
}

extern "C" void kernel_launch(void* const* d_in, const int* in_sizes, int n_in,
                              void* d_out, int out_size, void* d_ws, size_t ws_size,
                              hipStream_t stream)
{
    const float* feature = (const float*)d_in[0];
    const float* conv_w  = (const float*)d_in[1];
    const float* conv_b  = (const float*)d_in[2];
    const float* cent    = (const float*)d_in[3];
    const float* upfc_w  = (const float*)d_in[4];
    const float* upfc_b  = (const float*)d_in[5];
    const float* t1w     = (const float*)d_in[6];
    const float* t1b     = (const float*)d_in[7];
    const float* t2w     = (const float*)d_in[8];
    const float* t2b     = (const float*)d_in[9];

    float* ws = (float*)d_ws;                    // ~41.6 MB total
    unsigned short* xnb = (unsigned short*)ws;           // 16777216 us (32 MB)
    unsigned short* hb  = xnb;                           // alias: gemm1 writes in-place (block-exclusive px rows)
    float* rest  = ws + 8388608;
    float* rinv  = rest;                         // 65536
    float* sa    = rinv + 65536;                 // 2097152 (8 MB)
    float* up    = sa + 2097152;                 // 131072
    float* ssum  = up + 131072;                  // 512
    float* zpad  = ssum + 512;                   // 512 (zeroed: OOB redirect for glds)
    float* snorm = zpad + 512;                   // 65536
    float* upn   = snorm + 65536;                // 131072
    float* rowss = upn + 131072;                 // 512
    float* upvec = rowss + 512;                  // 4096
    float* t1up  = upvec + 4096;                 // 4096
    unsigned short* wbconv = (unsigned short*)upn;       // alias: upn written later by k_rowfix
    unsigned short* t1wb = (unsigned short*)sa;          // alias: sa dead after k_einsum
    unsigned short* t2wb = t1wb + 65536;
    float* out = (float*)d_out;

    hipMemsetAsync(up, 0, (131072 + 512 + 512) * sizeof(float), stream);  // up + ssum + zpad
    k_prep     <<<2048, 256, 0, stream>>>(feature, rinv, snorm, xnb);
    k_wpack    <<<288,  256, 0, stream>>>(conv_w, wbconv);
    k_conv     <<<2048, 128, 0, stream>>>(xnb, wbconv, conv_b, zpad, sa, ssum);
    k_einsum   <<<512,  256, 0, stream>>>(feature, rinv, sa, up);
    k_rowfix   <<<512,  256, 0, stream>>>(up, ssum, cent, upn, rowss);
    k_wpackp   <<<256,  256, 0, stream>>>(t1w, 512, t1wb);
    k_wpackp   <<<256,  256, 0, stream>>>(t2w, 256, t2wb);
    k_fc       <<<256,  256, 0, stream>>>(upn, rowss, upfc_w, upfc_b, upvec);
    k_t1up     <<<256,  256, 0, stream>>>(upvec, t1w, t1b, t1up);
    k_gemm1    <<<512,  512, 0, stream>>>(xnb, t1wb, t1up, snorm, hb);
    k_gemm2    <<<1024, 256, 0, stream>>>(hb, t2wb, t2b, out);
}

// Round 10
// 285.073 us; speedup vs baseline: 1.2009x; 1.0027x over previous
//
#include <hip/hip_runtime.h>
#include <cstdint>

#define N_ 16
#define C_ 256
#define H_ 64
#define W_ 64
#define L_ 4096          // H*W
#define K_ 32
#define CL_ (C_*L_)      // 1048576
#define KL_ (K_*L_)      // 131072
#define KC_ (K_*C_)      // 8192

typedef __attribute__((ext_vector_type(8))) short short8;   // 8 bf16 (4 VGPRs)
typedef __attribute__((ext_vector_type(4))) float f32x4;    // MFMA C/D frag

__device__ __forceinline__ unsigned short f2bf(float x) {   // RNE fp32->bf16
    unsigned int u = __float_as_uint(x);
    u += 0x7fffu + ((u >> 16) & 1u);
    return (unsigned short)(u >> 16);
}
__device__ __forceinline__ unsigned int pack2(float a, float b) {
    return (unsigned int)f2bf(a) | ((unsigned int)f2bf(b) << 16);
}

// async global->LDS, 16B per lane; dest = wave-uniform base + lane*16
__device__ __forceinline__ void glds16(const void* g, void* l) {
    __builtin_amdgcn_global_load_lds(
        (const __attribute__((address_space(1))) unsigned int*)g,
        (__attribute__((address_space(3))) unsigned int*)l, 16, 0, 0);
}

// ---------- K1: fused snorm + xn(bf16) transposed to (n,l,c) ----------
// Round-10: coalesced output stage. Old store was lane-strided 512B (64 x 16B
// segments/instr). Now: pack in regs (conflict-free tile reads, unchanged) ->
// bounce uint4s through LDS (reusing tile's storage, barrier-protected) ->
// cooperative store with 32 lanes x 16B = 512B contiguous (2 segments/instr).
// rinv dropped (einsum no longer needs it).
__global__ __launch_bounds__(256) void k_prep(
    const float* __restrict__ f, float* __restrict__ snorm,
    unsigned short* __restrict__ xnb)
{
    __shared__ float tile[256 * 34];            // [c][l], stride 34; reused as rpk
    __shared__ float ssred[8 * 33];
    __shared__ float rbuf[32];
    int bid = blockIdx.x;
    int n = bid >> 7;
    int l0 = (bid & 127) << 5;
    int tid = threadIdx.x;
    int l = tid & 31, cb = tid >> 5;            // cb 0..7
    const float* fp = f + (size_t)n * CL_ + l0 + l;
    float ss = 0.f;
#pragma unroll
    for (int i = 0; i < 32; ++i) {
        int c = (cb << 5) + i;
        float v = fp[(size_t)c * L_];
        tile[c * 34 + l] = v;
        ss = fmaf(v, v, ss);
    }
    ssred[cb * 33 + l] = ss;
    __syncthreads();
    if (tid < 32) {
        float s = 0.f;
#pragma unroll
        for (int j = 0; j < 8; ++j) s += ssred[j * 33 + tid];
        float sq = fmaxf(sqrtf(s), 1e-12f);
        snorm[n * L_ + l0 + tid] = sq;          // f = xn * snorm exactly (incl. clamp case)
        rbuf[tid] = 1.0f / sq;
    }
    __syncthreads();
    float ri = rbuf[l];
    uint4 pk4[4];
#pragma unroll
    for (int g = 0; g < 4; ++g) {
        unsigned int pk[4];
#pragma unroll
        for (int d = 0; d < 4; ++d) {
            int c = (cb << 5) + (g << 3) + (d << 1);
            pk[d] = pack2(tile[c * 34 + l] * ri, tile[(c + 1) * 34 + l] * ri);
        }
        pk4[g] = make_uint4(pk[0], pk[1], pk[2], pk[3]);
    }
    __syncthreads();                            // all tile reads done -> safe to reuse as rpk
    unsigned int* rpk = (unsigned int*)tile;    // [32 l][132 uints] (pad 4 -> bank spread)
#pragma unroll
    for (int g = 0; g < 4; ++g)
        *(uint4*)(rpk + l * 132 + (cb << 4) + (g << 2)) = pk4[g];
    __syncthreads();
    int col16 = tid & 31, rw = tid >> 5;        // store: 32 lanes = 512B contiguous/row
#pragma unroll
    for (int m2 = 0; m2 < 4; ++m2) {
        int row = (m2 << 3) + rw;
        uint4 v = *(const uint4*)(rpk + row * 132 + (col16 << 2));
        *(uint4*)(xnb + ((size_t)n * L_ + l0 + row) * C_ + (col16 << 3)) = v;
    }
}

// ---------- K2: repack conv weights -> wb[t][ch][q][k][8] bf16 ----------
__global__ __launch_bounds__(256) void k_wpack(const float* __restrict__ w, unsigned short* __restrict__ wb) {
    int i = blockIdx.x * 256 + threadIdx.x;     // 73728 = 9*8*4*256
    int j = i & 7;
    int k = (i >> 3) & 31;
    int q = (i >> 8) & 3;
    int ch = (i >> 10) & 7;
    int t = i >> 13;
    int c = (ch << 5) + (q << 3) + j;
    wb[i] = f2bf(w[k * 2304 + c * 9 + t]);
}

// ---------- K2b: panelized 256x256 weight pack for glds staging ----------
__global__ __launch_bounds__(256) void k_wpackp(const float* __restrict__ w, int stride,
                                                unsigned short* __restrict__ wb2) {
    int i = blockIdx.x * 256 + threadIdx.x;     // 65536
    int j = i & 7, co = (i >> 3) & 255, q = (i >> 11) & 3, ch = i >> 13;
    int ci = (ch << 5) + (q << 3) + j;
    wb2[i] = f2bf(w[(size_t)co * stride + ci]);
}

// ---------- K3: MFMA 3x3 conv, FULL async-LDS staging (r7-proven), fused softmax+ssum ----------
__global__ __launch_bounds__(128, 2) void k_conv(
    const unsigned short* __restrict__ xnb, const unsigned short* __restrict__ wb,
    const float* __restrict__ bias, const float* __restrict__ zpad,
    float* __restrict__ sa, float* __restrict__ ssum)
{
    __shared__ __align__(16) unsigned short lsB[2][408 * 8];    // 2 x 6528 B
    __shared__ __align__(16) unsigned short lsW[2][1152 * 8];   // 2 x 18432 B
    __shared__ float sred[2][32];
    int bid = blockIdx.x;                       // 2048 = px_b(2) x y(64) x n(16)
    int n = bid & 15, y = (bid >> 4) & 63, px_b = bid >> 10;   // XCD swizzle: n%8 = XCD
    int tid = threadIdx.x;
    int wv = tid >> 6, lane = tid & 63;
    int r = lane & 15, quad = lane >> 4;
    int pxw = (wv << 4) + r;                    // block-local out x (0..31)
    int xbase = (px_b << 5) - 1;                // input col of halo px 0
    const unsigned short* xb = xnb + (size_t)n * CL_;
    const unsigned short* zp = (const unsigned short*)zpad;

    // B staging: 408 cells; wave wv instr k covers cells [wv*64 + k*128, +64)
    const unsigned short* bsrc[4];
    bool bact[4];
#pragma unroll
    for (int k = 0; k < 4; ++k) {
        int c = (wv << 6) + (k << 7) + lane;
        bool act = c < 408;
        int cc = act ? c : 0;
        int row = cc / 136;
        int rem = cc - row * 136;
        int q = rem / 34;
        int px = rem - q * 34;
        int yy = y + row - 1, xx = xbase + px;
        bool ok = act && ((unsigned)yy < 64u) && ((unsigned)xx < 64u);
        bsrc[k] = ok ? (xb + (((size_t)(yy << 6) + xx) << 8) + (q << 3)) : zp;
        bact[k] = act;
    }

    f32x4 acc0 = (f32x4){0.f, 0.f, 0.f, 0.f};
    f32x4 acc1 = (f32x4){0.f, 0.f, 0.f, 0.f};

    // prologue: stage chunk 0 into buffer 0
    {
#pragma unroll
        for (int k = 0; k < 4; ++k)
            if (bact[k]) glds16(bsrc[k], lsB[0] + (((wv << 6) + (k << 7)) << 3));
#pragma unroll
        for (int k = 0; k < 9; ++k) {
            int idx = wv * 9 + k;               // 0..17
            int t = idx >> 1, h = idx & 1;
            glds16(wb + (t << 13) + (h << 9) + (lane << 3), lsW[0] + (idx << 9));
        }
    }

    for (int i = 0; i < 8; ++i) {
        asm volatile("s_waitcnt vmcnt(0)" ::: "memory");   // chunk i staged
        __syncthreads();
        if (i < 7) {                            // issue prefetch for chunk i+1 (other buffer)
            int c1 = (i + 1) << 5;              // B source advance: 32 shorts/chunk
            unsigned short* dB = lsB[(i + 1) & 1];
            unsigned short* dW = lsW[(i + 1) & 1];
#pragma unroll
            for (int k = 0; k < 4; ++k)
                if (bact[k]) glds16(bsrc[k] + c1, dB + (((wv << 6) + (k << 7)) << 3));
#pragma unroll
            for (int k = 0; k < 9; ++k) {
                int idx = wv * 9 + k;
                int t = idx >> 1, h = idx & 1;
                glds16(wb + (t << 13) + (h << 9) + ((i + 1) << 10) + (lane << 3),
                       dW + (idx << 9));
            }
        }
        // compute chunk i: pure LDS + MFMA
        const unsigned short* bufB = lsB[i & 1];
        const unsigned short* bufW = lsW[i & 1];
#pragma unroll
        for (int dy = 0; dy < 3; ++dy) {
#pragma unroll
            for (int dx = 0; dx < 3; ++dx) {
                int t = dy * 3 + dx;
                short8 B  = *(const short8*)(bufB + ((((dy << 2) + quad) * 34 + (pxw + dx)) << 3));
                short8 A0 = *(const short8*)(bufW + (((t << 7) + (quad << 5) + r) << 3));
                short8 A1 = *(const short8*)(bufW + (((t << 7) + (quad << 5) + 16 + r) << 3));
                acc0 = __builtin_amdgcn_mfma_f32_16x16x32_bf16(A0, B, acc0, 0, 0, 0);
                acc1 = __builtin_amdgcn_mfma_f32_16x16x32_bf16(A1, B, acc1, 0, 0, 0);
            }
        }
    }
    // bias + softmax over k (32 values per px: 4 quads x 8 regs)
    float4 b0 = *(const float4*)(bias + (quad << 2));
    float4 b1 = *(const float4*)(bias + 16 + (quad << 2));
    float v[8];
    v[0] = acc0[0] + b0.x; v[1] = acc0[1] + b0.y; v[2] = acc0[2] + b0.z; v[3] = acc0[3] + b0.w;
    v[4] = acc1[0] + b1.x; v[5] = acc1[1] + b1.y; v[6] = acc1[2] + b1.z; v[7] = acc1[3] + b1.w;
    float mx = v[0];
#pragma unroll
    for (int j = 1; j < 8; ++j) mx = fmaxf(mx, v[j]);
    mx = fmaxf(mx, __shfl_xor(mx, 16));
    mx = fmaxf(mx, __shfl_xor(mx, 32));
    float s = 0.f;
#pragma unroll
    for (int j = 0; j < 8; ++j) { v[j] = __expf(v[j] - mx); s += v[j]; }
    s += __shfl_xor(s, 16);
    s += __shfl_xor(s, 32);
    float rs = 1.0f / s;
    float sv8[8];
#pragma unroll
    for (int j = 0; j < 8; ++j) sv8[j] = v[j] * rs;
    int l = (y << 6) + (px_b << 5) + pxw;
    float* sp = sa + (size_t)n * KL_ + l;
#pragma unroll
    for (int j = 0; j < 4; ++j) {
        sp[(size_t)((quad << 2) + j) * L_] = sv8[j];
        sp[(size_t)(16 + (quad << 2) + j) * L_] = sv8[4 + j];
    }
    // fused ssum
#pragma unroll
    for (int j = 0; j < 8; ++j) {
        float a = sv8[j];
        a += __shfl_xor(a, 1); a += __shfl_xor(a, 2);
        a += __shfl_xor(a, 4); a += __shfl_xor(a, 8);
        sv8[j] = a;
    }
    if (r == 0) {
#pragma unroll
        for (int j = 0; j < 4; ++j) {
            sred[wv][(quad << 2) + j] = sv8[j];
            sred[wv][16 + (quad << 2) + j] = sv8[4 + j];
        }
    }
    __syncthreads();
    if (tid < 32) {
        float t = sred[0][tid] + sred[1][tid];
        atomicAdd(ssum + n * K_ + tid, t);
    }
}

// ---------- K5: up[n,k,c] += sum_l sa[n,k,l] * xn[n,c,l] ----------
// Round-10: reads xnb (bf16, 32 MB) instead of f+rinv (64 MB fp32) -- 1.8x less
// traffic, no VALU normalize. LDS layout [l][c] stride 257: inner xv reads are
// conflict-free (lanes cq consecutive; kq halves broadcast).
__global__ __launch_bounds__(256) void k_einsum(
    const unsigned short* __restrict__ xnb, const float* __restrict__ sa,
    float* __restrict__ up)
{
    __shared__ float xn_s[32 * 257];            // [l][c], stride 257
    __shared__ float sa_s[K_ * 32];
    int bid = blockIdx.x;                       // 512
    int n = bid >> 5;
    int l0 = (bid & 31) << 7;
    int tid = threadIdx.x;
    int kq = tid >> 5, cq = tid & 31;
    int rw = tid >> 5, col16 = tid & 31;        // staging map
    float acc[4][8];
#pragma unroll
    for (int i = 0; i < 4; ++i)
#pragma unroll
        for (int j = 0; j < 8; ++j) acc[i][j] = 0.f;

    for (int ch = 0; ch < 4; ++ch) {
        int lc = l0 + (ch << 5);
        __syncthreads();
#pragma unroll
        for (int m = 0; m < 4; ++m) {           // stage 32 l x 256 c bf16 -> f32
            int row = (m << 3) + rw;
            uint4 v = *(const uint4*)(xnb + ((size_t)n * L_ + lc + row) * C_ + (col16 << 3));
            float* d = xn_s + row * 257 + (col16 << 3);
            d[0] = __uint_as_float(v.x << 16); d[1] = __uint_as_float(v.x & 0xffff0000u);
            d[2] = __uint_as_float(v.y << 16); d[3] = __uint_as_float(v.y & 0xffff0000u);
            d[4] = __uint_as_float(v.z << 16); d[5] = __uint_as_float(v.z & 0xffff0000u);
            d[6] = __uint_as_float(v.w << 16); d[7] = __uint_as_float(v.w & 0xffff0000u);
        }
        {
            int k = tid >> 3, lq = (tid & 7) << 2;
            float4 a4 = *(const float4*)(sa + (size_t)n * KL_ + (size_t)k * L_ + lc + lq);
            *(float4*)(sa_s + (k << 5) + lq) = a4;
        }
        __syncthreads();
#pragma unroll 4
        for (int l = 0; l < 32; ++l) {
            float sv[4], xv[8];
#pragma unroll
            for (int i = 0; i < 4; ++i) sv[i] = sa_s[((kq << 2) + i) * 32 + l];
#pragma unroll
            for (int j = 0; j < 8; ++j) xv[j] = xn_s[l * 257 + cq + (j << 5)];
#pragma unroll
            for (int i = 0; i < 4; ++i)
#pragma unroll
                for (int j = 0; j < 8; ++j) acc[i][j] = fmaf(sv[i], xv[j], acc[i][j]);
        }
    }
    float* upp = up + (size_t)n * KC_;
#pragma unroll
    for (int i = 0; i < 4; ++i)
#pragma unroll
        for (int j = 0; j < 8; ++j)
            atomicAdd(upp + ((kq << 2) + i) * C_ + cq + (j << 5), acc[i][j]);
}

// ---------- K6: subtract centroid term, l2norm rows, record row sumsq ----------
__global__ __launch_bounds__(256) void k_rowfix(
    const float* __restrict__ up, const float* __restrict__ ssum,
    const float* __restrict__ cent, float* __restrict__ upn, float* __restrict__ rowss)
{
    __shared__ float red[256];
    int bid = blockIdx.x;                       // n*K + k
    int k = bid & 31;
    float sv = ssum[bid];
    float v = up[(size_t)bid * C_ + threadIdx.x] - sv * cent[k * C_ + threadIdx.x];
    red[threadIdx.x] = v * v; __syncthreads();
    for (int st = 128; st > 0; st >>= 1) {
        if (threadIdx.x < st) red[threadIdx.x] += red[threadIdx.x + st];
        __syncthreads();
    }
    float ss = red[0];
    float ri = 1.0f / fmaxf(sqrtf(ss), 1e-12f);
    upn[(size_t)bid * C_ + threadIdx.x] = v * ri;
    if (threadIdx.x == 0) rowss[bid] = ss * ri * ri;
}

// ---------- K7: global l2norm + FC, one block per output channel c ----------
__global__ __launch_bounds__(256) void k_fc(
    const float* __restrict__ upn, const float* __restrict__ rowss,
    const float* __restrict__ w, const float* __restrict__ b,
    float* __restrict__ upvec)
{
    __shared__ float rnb[16];
    __shared__ float red[16][5];
    int c = blockIdx.x;                         // 256
    int tid = threadIdx.x;
    int wv = tid >> 6, lane = tid & 63;
    if (tid < 16) {
        float ts = 0.f;
#pragma unroll
        for (int k = 0; k < K_; ++k) ts += rowss[(tid << 5) + k];
        rnb[tid] = 1.0f / fmaxf(sqrtf(ts), 1e-12f);
    }
    float acc[16];
#pragma unroll
    for (int n = 0; n < 16; ++n) acc[n] = 0.f;
    const float* wr = w + (size_t)c * KC_;
#pragma unroll
    for (int g = 0; g < 8; ++g) {
        int kc = (g << 10) + (tid << 2);
        float4 w4 = *(const float4*)(wr + kc);
#pragma unroll
        for (int n = 0; n < 16; ++n) {
            float4 u4 = *(const float4*)(upn + n * KC_ + kc);
            acc[n] += w4.x * u4.x + w4.y * u4.y + w4.z * u4.z + w4.w * u4.w;
        }
    }
#pragma unroll
    for (int n = 0; n < 16; ++n) {
        float a = acc[n];
#pragma unroll
        for (int s = 1; s < 64; s <<= 1) a += __shfl_xor(a, s);
        if (lane == 0) red[n][wv] = a;
    }
    __syncthreads();
    if (tid < 16) {
        float v = red[tid][0] + red[tid][1] + red[tid][2] + red[tid][3];
        upvec[tid * C_ + c] = v * rnb[tid] + b[c];
    }
}

// ---------- K8: t1up[n,co] = t1_w[co,256:512] . upvec[n,:] + t1_b[co] ----------
__global__ __launch_bounds__(256) void k_t1up(
    const float* __restrict__ upvec, const float* __restrict__ t1w,
    const float* __restrict__ t1b, float* __restrict__ t1up)
{
    __shared__ float wld[256];
    int co = blockIdx.x;                        // 256
    int tid = threadIdx.x;
    wld[tid] = t1w[(size_t)co * 512 + 256 + tid];
    __syncthreads();
    int n = tid >> 4, s = tid & 15;
    float a = 0.f;
#pragma unroll
    for (int i = 0; i < 16; ++i)
        a += wld[s + (i << 4)] * upvec[n * C_ + s + (i << 4)];
#pragma unroll
    for (int st = 1; st < 16; st <<= 1) a += __shfl_xor(a, st);
    if (s == 0) t1up[n * C_ + co] = a + t1b[co];
}

// ---------- K9: MFMA gemm1 -- FULL async-LDS staging from xnb (bf16), merged-co ----------
__global__ __launch_bounds__(512, 2) void k_gemm1(
    const unsigned short* __restrict__ xnb, const unsigned short* __restrict__ wb2,
    const float* __restrict__ t1up, const float* __restrict__ snorm,
    unsigned short* __restrict__ hb)
{
    __shared__ __align__(16) unsigned short lsB[2][512 * 8];    // 2 x 8 KB: [q(4)][px(128)]
    __shared__ __align__(16) unsigned short lsW[2][1024 * 8];   // 2 x 16 KB: [q(4)][co(256)]
    int bid = blockIdx.x;                       // 512 = px_b(32) x n(16)
    int n = bid & 15, px_b = bid >> 4;          // XCD swizzle: n%8 = XCD
    int l0 = px_b << 7;
    int tid = threadIdx.x;
    int wv = tid >> 6, lane = tid & 63;
    int r = lane & 15, quad = lane >> 4;
    int pxl = (wv >> 2) << 6;                   // 0 or 64
    int co0 = (wv & 3) << 6;                    // 0,64,128,192
    const unsigned short* xrow = xnb + ((size_t)n * L_ + l0) * C_;

    int cbi = (wv << 6) + lane;
    int bq = cbi >> 7, bpx = cbi & 127;
    const unsigned short* bsrc = xrow + (size_t)bpx * C_ + (bq << 3);

    glds16(bsrc, lsB[0] + (cbi << 3));
#pragma unroll
    for (int k = 0; k < 2; ++k) {
        int cw = (wv << 7) + (k << 6) + lane;   // [0,1024)
        glds16(wb2 + ((size_t)cw << 3), lsW[0] + (cw << 3));
    }

    f32x4 acc[4][4];
#pragma unroll
    for (int i = 0; i < 4; ++i)
#pragma unroll
        for (int j = 0; j < 4; ++j) acc[i][j] = (f32x4){0.f, 0.f, 0.f, 0.f};

    for (int i = 0; i < 8; ++i) {
        asm volatile("s_waitcnt vmcnt(0)" ::: "memory");   // chunk i staged
        __syncthreads();
        if (i < 7) {
            glds16(bsrc + ((i + 1) << 5), lsB[(i + 1) & 1] + (cbi << 3));
#pragma unroll
            for (int k = 0; k < 2; ++k) {
                int cw = (wv << 7) + (k << 6) + lane;
                glds16(wb2 + ((size_t)(((i + 1) << 10) + cw) << 3),
                       lsW[(i + 1) & 1] + (cw << 3));
            }
        }
        const unsigned short* bufB = lsB[i & 1];
        const unsigned short* bufW = lsW[i & 1];
        short8 A[4], B[4];
#pragma unroll
        for (int t = 0; t < 4; ++t)
            A[t] = *(const short8*)(bufW + (((quad << 8) + co0 + (t << 4) + r) << 3));
#pragma unroll
        for (int t = 0; t < 4; ++t)
            B[t] = *(const short8*)(bufB + (((quad << 7) + pxl + (t << 4) + r) << 3));
#pragma unroll
        for (int pxt = 0; pxt < 4; ++pxt)
#pragma unroll
            for (int cot = 0; cot < 4; ++cot)
                acc[pxt][cot] = __builtin_amdgcn_mfma_f32_16x16x32_bf16(A[cot], B[pxt], acc[pxt][cot], 0, 0, 0);
    }
#pragma unroll
    for (int pxt = 0; pxt < 4; ++pxt) {
        int px = l0 + pxl + (pxt << 4) + r;
        float sc = snorm[n * L_ + px];
        unsigned short* orow = hb + ((size_t)n * L_ + px) * C_;
#pragma unroll
        for (int cot = 0; cot < 4; ++cot) {
            int cb = co0 + (cot << 4) + (quad << 2);
            float4 bb = *(const float4*)(t1up + n * C_ + cb);
            unsigned int p0 = pack2(fmaxf(fmaf(acc[pxt][cot][0], sc, bb.x), 0.f),
                                    fmaxf(fmaf(acc[pxt][cot][1], sc, bb.y), 0.f));
            unsigned int p1 = pack2(fmaxf(fmaf(acc[pxt][cot][2], sc, bb.z), 0.f),
                                    fmaxf(fmaf(acc[pxt][cot][3], sc, bb.w), 0.f));
            *(uint2*)(orow + cb) = make_uint2(p0, p1);
        }
    }
}

// ---------- K10: MFMA gemm2 -- FULL async-LDS staging (B and W via glds) ----------
__global__ __launch_bounds__(256) void k_gemm2(
    const unsigned short* __restrict__ hb, const unsigned short* __restrict__ wb2,
    const float* __restrict__ t2b, float* __restrict__ out)
{
    __shared__ __align__(16) unsigned short lsB[2][512 * 8];    // 2 x 8192 B
    __shared__ __align__(16) unsigned short lsW[2][512 * 8];    // 2 x 8192 B
    int bid = blockIdx.x;                       // 1024
    int co_b = bid & 1, px_b = (bid >> 1) & 31, n = bid >> 6;
    int l0 = px_b << 7;
    int tid = threadIdx.x;
    int wv = tid >> 6, lane = tid & 63;
    int r = lane & 15, quad = lane >> 4;
    int pxl = (wv >> 1) << 6;
    int co0l = (wv & 1) << 6;
    int co0 = (co_b << 7) + co0l;
    const unsigned short* hrow = hb + ((size_t)n * L_ + l0) * C_;

#pragma unroll
    for (int k = 0; k < 2; ++k) {
        glds16(hrow + (size_t)((k << 6) + lane) * C_ + (wv << 3),
               lsB[0] + (((wv << 7) + (k << 6)) << 3));
        glds16(wb2 + (((wv << 8) + (co_b << 7) + (k << 6) + lane) << 3),
               lsW[0] + (((wv << 7) + (k << 6)) << 3));
    }

    f32x4 acc[4][4];
#pragma unroll
    for (int i = 0; i < 4; ++i)
#pragma unroll
        for (int j = 0; j < 4; ++j) acc[i][j] = (f32x4){0.f, 0.f, 0.f, 0.f};

    for (int i = 0; i < 8; ++i) {
        asm volatile("s_waitcnt vmcnt(0)" ::: "memory");   // chunk i staged
        __syncthreads();
        if (i < 7) {
#pragma unroll
            for (int k = 0; k < 2; ++k) {
                glds16(hrow + (size_t)((k << 6) + lane) * C_ + ((i + 1) << 5) + (wv << 3),
                       lsB[(i + 1) & 1] + (((wv << 7) + (k << 6)) << 3));
                glds16(wb2 + ((((((i + 1) << 2) + wv) << 8) + (co_b << 7) + (k << 6) + lane) << 3),
                       lsW[(i + 1) & 1] + (((wv << 7) + (k << 6)) << 3));
            }
        }
        const unsigned short* bufB = lsB[i & 1];
        const unsigned short* bufW = lsW[i & 1];
        short8 A[4], B[4];
#pragma unroll
        for (int t = 0; t < 4; ++t)
            A[t] = *(const short8*)(bufW + (((quad << 7) + co0l + (t << 4) + r) << 3));
#pragma unroll
        for (int t = 0; t < 4; ++t)
            B[t] = *(const short8*)(bufB + (((quad << 7) + pxl + (t << 4) + r) << 3));
#pragma unroll
        for (int pxt = 0; pxt < 4; ++pxt)
#pragma unroll
            for (int cot = 0; cot < 4; ++cot)
                acc[pxt][cot] = __builtin_amdgcn_mfma_f32_16x16x32_bf16(A[cot], B[pxt], acc[pxt][cot], 0, 0, 0);
    }
#pragma unroll
    for (int pxt = 0; pxt < 4; ++pxt) {
        int px = l0 + pxl + (pxt << 4) + r;
#pragma unroll
        for (int cot = 0; cot < 4; ++cot) {
            int cb = co0 + (cot << 4) + (quad << 2);
            float4 bb = *(const float4*)(t2b + cb);
            out[((size_t)n * C_ + cb + 0) * L_ + px] = fmaxf(acc[pxt][cot][0] + bb.x, 0.f);
            out[((size_t)n * C_ + cb + 1) * L_ + px] = fmaxf(acc[pxt][cot][1] + bb.y, 0.f);
            out[((size_t)n * C_ + cb + 2) * L_ + px] = fmaxf(acc[pxt][cot][2] + bb.z, 0.f);
            out[((size_t)n * C_ + cb + 3) * L_ + px] = fmaxf(acc[pxt][cot][3] + bb.w, 0.f);
        }
    }
}

extern "C" void kernel_launch(void* const* d_in, const int* in_sizes, int n_in,
                              void* d_out, int out_size, void* d_ws, size_t ws_size,
                              hipStream_t stream)
{
    const float* feature = (const float*)d_in[0];
    const float* conv_w  = (const float*)d_in[1];
    const float* conv_b  = (const float*)d_in[2];
    const float* cent    = (const float*)d_in[3];
    const float* upfc_w  = (const float*)d_in[4];
    const float* upfc_b  = (const float*)d_in[5];
    const float* t1w     = (const float*)d_in[6];
    const float* t1b     = (const float*)d_in[7];
    const float* t2w     = (const float*)d_in[8];
    const float* t2b     = (const float*)d_in[9];

    float* ws = (float*)d_ws;                    // ~41.6 MB total
    unsigned short* xnb = (unsigned short*)ws;           // 16777216 us (32 MB)
    unsigned short* hb  = xnb;                           // alias: gemm1 writes in-place (block-exclusive px rows)
    float* rest  = ws + 8388608;
    float* rinv  = rest;                         // 65536 (unused this round; slot kept)
    float* sa    = rinv + 65536;                 // 2097152 (8 MB)
    float* up    = sa + 2097152;                 // 131072
    float* ssum  = up + 131072;                  // 512
    float* zpad  = ssum + 512;                   // 512 (zeroed: OOB redirect for glds)
    float* snorm = zpad + 512;                   // 65536
    float* upn   = snorm + 65536;                // 131072
    float* rowss = upn + 131072;                 // 512
    float* upvec = rowss + 512;                  // 4096
    float* t1up  = upvec + 4096;                 // 4096
    unsigned short* wbconv = (unsigned short*)upn;       // alias: upn written later by k_rowfix
    unsigned short* t1wb = (unsigned short*)sa;          // alias: sa dead after k_einsum
    unsigned short* t2wb = t1wb + 65536;
    float* out = (float*)d_out;

    hipMemsetAsync(up, 0, (131072 + 512 + 512) * sizeof(float), stream);  // up + ssum + zpad
    k_prep     <<<2048, 256, 0, stream>>>(feature, snorm, xnb);
    k_wpack    <<<288,  256, 0, stream>>>(conv_w, wbconv);
    k_conv     <<<2048, 128, 0, stream>>>(xnb, wbconv, conv_b, zpad, sa, ssum);
    k_einsum   <<<512,  256, 0, stream>>>(xnb, sa, up);
    k_rowfix   <<<512,  256, 0, stream>>>(up, ssum, cent, upn, rowss);
    k_wpackp   <<<256,  256, 0, stream>>>(t1w, 512, t1wb);
    k_wpackp   <<<256,  256, 0, stream>>>(t2w, 256, t2wb);
    k_fc       <<<256,  256, 0, stream>>>(upn, rowss, upfc_w, upfc_b, upvec);
    k_t1up     <<<256,  256, 0, stream>>>(upvec, t1w, t1b, t1up);
    k_gemm1    <<<512,  512, 0, stream>>>(xnb, t1wb, t1up, snorm, hb);
    k_gemm2    <<<1024, 256, 0, stream>>>(hb, t2wb, t2b, out);
}